// Round 14
// baseline (132.255 us; speedup 1.0000x reference)
//
#include <hip/hip_runtime.h>
#include <hip/hip_bf16.h>
#include <math.h>

// Problem: B=1, T=2048, E=1024, H=16, DH=64, NB=10, ML=2048
// Pipeline (all bf16 MFMA):
//   prep_mega: Xb = bf16(X); WbT = [Wq*0.125*log2e|Wk|Wv|Wr]^T; WpT; bias
//   gemm1: Y[2048][3328] = Xb @ Wb + bias   (Q|K|V|R)
//   post_mega: Vt[h][d][t] = V^T per head; BndT*log2e table (WbT pad rows)
//   attn: 1024 uniform 1-wave blocks (pair p: qbA=31-p then qbB=p; 33 iters),
//         K/V double-buffer, zero barriers, vmcnt(0) drain at iter end,
//         softmax in exp2 domain (log2e prefolded)
//   gemm2 (64x128 tiles, 256 blocks): out = AO @ Wp + bp (f32)

typedef __attribute__((ext_vector_type(8))) short bf16x8;
typedef __attribute__((ext_vector_type(4))) float f32x4;

#define MFMA16(a,b,c) __builtin_amdgcn_mfma_f32_16x16x32_bf16((a),(b),(c),0,0,0)
#define GLB(p)  ((const __attribute__((address_space(1))) void*)(p))
#define LDSP(p) ((__attribute__((address_space(3))) void*)(p))
#define LDY2 3328
#define LOG2E 1.44269504088896f

__device__ __forceinline__ unsigned short f2bf(float x){
  unsigned u = __float_as_uint(x);
  u = (u + 0x7FFFu + ((u >> 16) & 1u)) >> 16;
  return (unsigned short)u;
}
__device__ __forceinline__ unsigned short f2bf_rn(float x){
  __hip_bfloat16 b = __float2bfloat16(x);
  return *reinterpret_cast<unsigned short*>(&b);
}
__device__ __forceinline__ float bf2f(unsigned short b){
  return __uint_as_float(((unsigned)b) << 16);
}

// ---------------- fused prep kernel (convert_x | pack_wbt | transpose_wp | bias)

__global__ __launch_bounds__(256) void prep_mega(
    const float* __restrict__ X,
    const float* __restrict__ Wq, const float* __restrict__ Wk,
    const float* __restrict__ Wv, const float* __restrict__ Wr,
    const float* __restrict__ Wp,
    const float* __restrict__ bq, const float* __restrict__ br,
    unsigned short* __restrict__ Xb, unsigned short* __restrict__ WbT,
    unsigned short* __restrict__ WpT, float* __restrict__ bias)
{
  __shared__ float tile[64][65];
  const int b = blockIdx.x;
  const int tid = threadIdx.x;

  if (b < 1024){
    const int i = (b * 256 + tid) * 8;
    f32x4 a = *(const f32x4*)(X + i);
    f32x4 v2 = *(const f32x4*)(X + i + 4);
    bf16x8 v;
    v[0]=(short)f2bf(a.x); v[1]=(short)f2bf(a.y); v[2]=(short)f2bf(a.z); v[3]=(short)f2bf(a.w);
    v[4]=(short)f2bf(v2.x); v[5]=(short)f2bf(v2.y); v[6]=(short)f2bf(v2.z); v[7]=(short)f2bf(v2.w);
    *(bf16x8*)(Xb + i) = v;
    return;
  }
  if (b < 1024 + 832){
    const int idx = b - 1024;
    const int k0 = (idx & 15) * 64, c0 = (idx >> 4) * 64;
    {
      const int r = tid >> 2, cs = (tid & 3) << 4;
      #pragma unroll
      for (int q = 0; q < 4; ++q){
        const int c = c0 + cs + q * 4;
        f32x4 v;
        if (c < 1024){
          v = *(const f32x4*)(Wq + (size_t)(k0+r)*1024 + c);
          const float s = 0.125f * LOG2E;   // fold 1/sqrt(d) and log2e into Q
          v.x *= s; v.y *= s; v.z *= s; v.w *= s;
        }
        else if (c < 2048) v = *(const f32x4*)(Wk + (size_t)(k0+r)*1024 + (c-1024));
        else if (c < 3072) v = *(const f32x4*)(Wv + (size_t)(k0+r)*1024 + (c-2048));
        else if (c < 3232) v = *(const f32x4*)(Wr + (size_t)(k0+r)*160  + (c-3072));
        else               v = (f32x4){0.f,0.f,0.f,0.f};
        tile[r][cs+q*4+0]=v.x; tile[r][cs+q*4+1]=v.y; tile[r][cs+q*4+2]=v.z; tile[r][cs+q*4+3]=v.w;
      }
    }
    __syncthreads();
    const int c = tid >> 2, ks = (tid & 3) << 4;
    bf16x8 o0, o1;
    #pragma unroll
    for (int x = 0; x < 8; ++x) o0[x] = (short)f2bf(tile[ks + x][c]);
    #pragma unroll
    for (int x = 0; x < 8; ++x) o1[x] = (short)f2bf(tile[ks + 8 + x][c]);
    *(bf16x8*)(WbT + (size_t)(c0 + c) * 1024 + k0 + ks)     = o0;
    *(bf16x8*)(WbT + (size_t)(c0 + c) * 1024 + k0 + ks + 8) = o1;
    return;
  }
  if (b < 1024 + 832 + 256){
    const int idx = b - 1856;
    const int k0 = (idx & 15) * 64, c0 = (idx >> 4) * 64;
    {
      const int r = tid >> 2, cs = (tid & 3) << 4;
      #pragma unroll
      for (int q = 0; q < 4; ++q){
        f32x4 v = *(const f32x4*)(Wp + (size_t)(k0+r)*1024 + c0 + cs + q*4);
        tile[r][cs+q*4+0]=v.x; tile[r][cs+q*4+1]=v.y; tile[r][cs+q*4+2]=v.z; tile[r][cs+q*4+3]=v.w;
      }
    }
    __syncthreads();
    const int c = tid >> 2, ks = (tid & 3) << 4;
    bf16x8 o0, o1;
    #pragma unroll
    for (int x = 0; x < 8; ++x) o0[x] = (short)f2bf(tile[ks + x][c]);
    #pragma unroll
    for (int x = 0; x < 8; ++x) o1[x] = (short)f2bf(tile[ks + 8 + x][c]);
    *(bf16x8*)(WpT + (size_t)(c0 + c) * 1024 + k0 + ks)     = o0;
    *(bf16x8*)(WpT + (size_t)(c0 + c) * 1024 + k0 + ks + 8) = o1;
    return;
  }
  const int c = (b - 2112) * 256 + tid;
  if (c < 3328){
    float v = 0.f;
    if (c < 1024) v = bq[c] * 0.125f * LOG2E;
    else if (c >= 3072 && c < 3232) v = br[c - 3072];
    bias[c] = v;
  }
}

// ---------------- fused post kernel (vt_transpose | build_bndt) --------------

__global__ __launch_bounds__(256) void post_mega(
    const unsigned short* __restrict__ Y, const float* __restrict__ bnd,
    unsigned short* __restrict__ Vt, unsigned short* __restrict__ BndT)
{
  __shared__ unsigned short tile[64][72];
  const int b = blockIdx.x;
  const int tid = threadIdx.x;

  if (b < 512){
    const int h = b >> 5, t0 = (b & 31) * 64;
    {
      const int r = tid >> 2, cs = (tid & 3) << 4;
      const unsigned short* src = Y + (size_t)(t0 + r) * LDY2 + 2048 + h * 64 + cs;
      *(bf16x8*)&tile[r][cs]     = *(const bf16x8*)src;
      *(bf16x8*)&tile[r][cs + 8] = *(const bf16x8*)(src + 8);
    }
    __syncthreads();
    const int d = tid >> 2, ts = (tid & 3) << 4;
    bf16x8 o0, o1;
    #pragma unroll
    for (int x = 0; x < 8; ++x) o0[x] = (short)tile[ts + x][d];
    #pragma unroll
    for (int x = 0; x < 8; ++x) o1[x] = (short)tile[ts + 8 + x][d];
    *(bf16x8*)(Vt + (size_t)(h*64 + d) * 2048 + t0 + ts)     = o0;
    *(bf16x8*)(Vt + (size_t)(h*64 + d) * 2048 + t0 + ts + 8) = o1;
    return;
  }
  // BndT[t'][32] scaled by log2e (E contributes to exp2-domain logits)
  const int t = (b - 512) * 256 + tid;
  if (t >= 2176) return;
  const int rel = t - 64;
  unsigned short* dst = BndT + (size_t)t * 32;
  bf16x8 v0 = {}, v1 = {}, z = {};
  if (rel >= 0 && rel < 2048){
    #pragma unroll
    for (int n = 0; n < 8; ++n) v0[n] = (short)f2bf(bnd[n * 2048 + rel] * LOG2E);
    v1[0] = (short)f2bf(bnd[8 * 2048 + rel] * LOG2E);
    v1[1] = (short)f2bf(bnd[9 * 2048 + rel] * LOG2E);
  }
  *(bf16x8*)dst        = v0;
  *(bf16x8*)(dst + 8)  = v1;
  *(bf16x8*)(dst + 16) = z;
  *(bf16x8*)(dst + 24) = z;
}

// ---------------- bf16 MFMA GEMM, 128x128 tile (projection) -----------------

__global__ __launch_bounds__(256) void gemm_bf16(
    const unsigned short* __restrict__ A,
    const unsigned short* __restrict__ BT,
    const float* __restrict__ bias,
    unsigned short* __restrict__ C, int ldc)
{
  __shared__ unsigned short As[128 * 64];
  __shared__ unsigned short Bs[128 * 64];
  const int tid = threadIdx.x;
  const int w = tid >> 6, lane = tid & 63;
  const int lid = lane & 15, lgrp = lane >> 4;
  const int wm = w >> 1, wn = w & 1;
  const int row0 = blockIdx.y << 7, col0 = blockIdx.x << 7;
  const int sr = lane >> 3;
  const int sc = (lane & 7) ^ sr;

  f32x4 acc[4][4] = {};

  for (int k0 = 0; k0 < 1024; k0 += 64){
    #pragma unroll
    for (int it = 0; it < 4; ++it){
      const int r0w = (w << 5) + (it << 3);
      const int r = r0w + sr;
      __builtin_amdgcn_global_load_lds(GLB(A  + (size_t)(row0 + r) * 1024 + k0 + (sc << 3)),
                                       LDSP(&As[r0w << 6]), 16, 0, 0);
      __builtin_amdgcn_global_load_lds(GLB(BT + (size_t)(col0 + r) * 1024 + k0 + (sc << 3)),
                                       LDSP(&Bs[r0w << 6]), 16, 0, 0);
    }
    __syncthreads();

    bf16x8 af[4][2], bfr[4][2];
    #pragma unroll
    for (int m = 0; m < 4; ++m){
      const int ra = wm * 64 + m * 16 + lid;
      const int rb = wn * 64 + m * 16 + lid;
      #pragma unroll
      for (int kk = 0; kk < 2; ++kk){
        const int kc = kk * 4 + lgrp;
        af[m][kk]  = *(const bf16x8*)&As[(ra << 6) + ((kc ^ (lid & 7)) << 3)];
        bfr[m][kk] = *(const bf16x8*)&Bs[(rb << 6) + ((kc ^ (lid & 7)) << 3)];
      }
    }
    #pragma unroll
    for (int m = 0; m < 4; ++m)
      #pragma unroll
      for (int n = 0; n < 4; ++n){
        acc[m][n] = MFMA16(af[m][0], bfr[n][0], acc[m][n]);
        acc[m][n] = MFMA16(af[m][1], bfr[n][1], acc[m][n]);
      }
    __syncthreads();
  }

  #pragma unroll
  for (int m = 0; m < 4; ++m){
    #pragma unroll
    for (int n = 0; n < 4; ++n){
      const int col = col0 + wn * 64 + n * 16 + lid;
      const float bv = bias[col];
      #pragma unroll
      for (int i = 0; i < 4; ++i){
        const int row = row0 + wm * 64 + m * 16 + lgrp * 4 + i;
        C[(size_t)row * ldc + col] = f2bf(acc[m][n][i] + bv);
      }
    }
  }
}

// ---------------- bf16 MFMA GEMM, 64x128 tile, f32 out (out-projection) -----

__global__ __launch_bounds__(256) void gemm_bf16_out(
    const unsigned short* __restrict__ A,
    const unsigned short* __restrict__ BT,
    const float* __restrict__ bias,
    float* __restrict__ C)
{
  __shared__ unsigned short As[64 * 64];
  __shared__ unsigned short Bs[128 * 64];
  const int tid = threadIdx.x;
  const int w = tid >> 6, lane = tid & 63;
  const int lid = lane & 15, lgrp = lane >> 4;
  const int wm = w >> 1, wn = w & 1;
  const int row0 = blockIdx.y << 6, col0 = blockIdx.x << 7;
  const int sr = lane >> 3;
  const int sc = (lane & 7) ^ sr;

  f32x4 acc[2][4] = {};

  for (int k0 = 0; k0 < 1024; k0 += 64){
    #pragma unroll
    for (int it = 0; it < 2; ++it){
      const int r0w = (w << 4) + (it << 3);
      const int r = r0w + sr;
      __builtin_amdgcn_global_load_lds(GLB(A + (size_t)(row0 + r) * 1024 + k0 + (sc << 3)),
                                       LDSP(&As[r0w << 6]), 16, 0, 0);
    }
    #pragma unroll
    for (int it = 0; it < 4; ++it){
      const int r0w = (w << 5) + (it << 3);
      const int r = r0w + sr;
      __builtin_amdgcn_global_load_lds(GLB(BT + (size_t)(col0 + r) * 1024 + k0 + (sc << 3)),
                                       LDSP(&Bs[r0w << 6]), 16, 0, 0);
    }
    __syncthreads();

    bf16x8 af[2][2], bfr[4][2];
    #pragma unroll
    for (int m = 0; m < 2; ++m){
      const int ra = wm * 32 + m * 16 + lid;
      #pragma unroll
      for (int kk = 0; kk < 2; ++kk){
        const int kc = kk * 4 + lgrp;
        af[m][kk] = *(const bf16x8*)&As[(ra << 6) + ((kc ^ (lid & 7)) << 3)];
      }
    }
    #pragma unroll
    for (int n = 0; n < 4; ++n){
      const int rb = wn * 64 + n * 16 + lid;
      #pragma unroll
      for (int kk = 0; kk < 2; ++kk){
        const int kc = kk * 4 + lgrp;
        bfr[n][kk] = *(const bf16x8*)&Bs[(rb << 6) + ((kc ^ (lid & 7)) << 3)];
      }
    }
    #pragma unroll
    for (int m = 0; m < 2; ++m)
      #pragma unroll
      for (int n = 0; n < 4; ++n){
        acc[m][n] = MFMA16(af[m][0], bfr[n][0], acc[m][n]);
        acc[m][n] = MFMA16(af[m][1], bfr[n][1], acc[m][n]);
      }
    __syncthreads();
  }

  #pragma unroll
  for (int m = 0; m < 2; ++m){
    #pragma unroll
    for (int n = 0; n < 4; ++n){
      const int col = col0 + wn * 64 + n * 16 + lid;
      const float bv = bias[col];
      #pragma unroll
      for (int i = 0; i < 4; ++i){
        const int row = row0 + wm * 32 + m * 16 + lgrp * 4 + i;
        C[(size_t)row * 1024 + col] = acc[m][n][i] + bv;
      }
    }
  }
}

// ---------------- fused flash attention -------------------------------------
// 1024 uniform 1-wave blocks (64 thr). Block = (pair p, quarter u, h):
// processes rows of qbA=31-p over qbA's kv range, then rows of qbB=p.
// Every block = exactly 33 tile-iters; all 4 blocks/CU resident to the end.
// K/V double-buffered; zero barriers (single wave); per iter:
//   bw(t) loads -> stage(t+1) into buf^1 -> body(buf) -> vmcnt(0) drain.
// Softmax in exp2 domain (log2e folded into Q and BndT).

__device__ __forceinline__ void stage_tile(
    const unsigned short* __restrict__ Y,
    const unsigned short* __restrict__ Vt,
    unsigned short* __restrict__ Ksb,
    unsigned short* __restrict__ Vsb,
    int j0, int h, int sr, int scc)
{
  #pragma unroll
  for (int st = 0; st < 8; ++st){
    const int r0w = st * 8;
    const int r = r0w + sr;
    __builtin_amdgcn_global_load_lds(
        GLB(Y + (size_t)(j0 + r) * LDY2 + 1024 + h*64 + (scc << 3)),
        LDSP(&Ksb[r0w << 6]), 16, 0, 0);
    __builtin_amdgcn_global_load_lds(
        GLB(Vt + (size_t)(h*64 + r) * 2048 + j0 + (scc << 3)),
        LDSP(&Vsb[r0w << 6]), 16, 0, 0);
  }
}

__device__ __forceinline__ void attn_tile_body(
    const unsigned short* __restrict__ Ksb,
    const unsigned short* __restrict__ Vsb,
    unsigned short* __restrict__ un,
    const bf16x8 (&bw)[5],
    const bf16x8 (&qf)[2], const bf16x8& rf,
    int lid, int lgrp,
    bool diag, int ql,
    float& m_i, float& l_i, f32x4 (&o)[4])
{
  // S^T = K Q^T : s[n4][i] = S[q=lid][j = n4*16 + lgrp*4 + i]  (exp2 domain)
  f32x4 s[4] = {};
  __builtin_amdgcn_s_setprio(1);
  #pragma unroll
  for (int kk = 0; kk < 2; ++kk){
    const int kc = kk * 4 + lgrp;
    #pragma unroll
    for (int n4 = 0; n4 < 4; ++n4){
      const bf16x8 kf = *(const bf16x8*)&Ksb[((n4*16 + lid) << 6) + ((kc ^ (lid & 7)) << 3)];
      s[n4] = MFMA16(kf, qf[kk], s[n4]);
    }
  }
  __builtin_amdgcn_s_setprio(0);

  // E window via MFMA -> bf16 el[q][c], c = f*16+lid
  #pragma unroll
  for (int f = 0; f < 5; ++f){
    f32x4 ef = {};
    ef = MFMA16(rf, bw[f], ef);
    #pragma unroll
    for (int i = 0; i < 4; ++i)
      un[(lgrp*4 + i) * 80 + f*16 + lid] = f2bf_rn(ef[i]);
  }

  // bias gather + causal mask
  #pragma unroll
  for (int n4 = 0; n4 < 4; ++n4){
    #pragma unroll
    for (int i = 0; i < 4; ++i){
      const int jl = n4*16 + lgrp*4 + i;
      float v = s[n4][i] + bf2f(un[lid * 80 + (lid - jl + 63)]);
      if (diag && jl > ql) v = -1e9f;
      s[n4][i] = v;
    }
  }

  // in-register online softmax (exp2 domain), defer-max THR = 8*log2e
  float rm = s[0][0];
  #pragma unroll
  for (int n4 = 0; n4 < 4; ++n4)
    #pragma unroll
    for (int i = 0; i < 4; ++i) rm = fmaxf(rm, s[n4][i]);
  rm = fmaxf(rm, __shfl_xor(rm, 16));
  rm = fmaxf(rm, __shfl_xor(rm, 32));

  if (__all(rm - m_i <= 11.54f)){
    float rs = 0.f;
    #pragma unroll
    for (int n4 = 0; n4 < 4; ++n4)
      #pragma unroll
      for (int i = 0; i < 4; ++i){
        const float pv = __builtin_amdgcn_exp2f(s[n4][i] - m_i);
        s[n4][i] = pv;
        rs += pv;
      }
    rs += __shfl_xor(rs, 16);
    rs += __shfl_xor(rs, 32);
    l_i += rs;
  } else {
    const float mn = fmaxf(m_i, rm);
    const float sc_ = __builtin_amdgcn_exp2f(m_i - mn);
    m_i = mn;
    float rs = 0.f;
    #pragma unroll
    for (int n4 = 0; n4 < 4; ++n4)
      #pragma unroll
      for (int i = 0; i < 4; ++i){
        const float pv = __builtin_amdgcn_exp2f(s[n4][i] - mn);
        s[n4][i] = pv;
        rs += pv;
      }
    rs += __shfl_xor(rs, 16);
    rs += __shfl_xor(rs, 32);
    l_i = l_i * sc_ + rs;
    #pragma unroll
    for (int n4 = 0; n4 < 4; ++n4)
      #pragma unroll
      for (int i = 0; i < 4; ++i) o[n4][i] *= sc_;
  }

  // P -> wave-local LDS (union region; el reads above complete first)
  #pragma unroll
  for (int n4 = 0; n4 < 4; ++n4){
    const unsigned a = ((unsigned)f2bf_rn(s[n4][0])) | (((unsigned)f2bf_rn(s[n4][1])) << 16);
    const unsigned b = ((unsigned)f2bf_rn(s[n4][2])) | (((unsigned)f2bf_rn(s[n4][3])) << 16);
    const int chunk = (n4*2 + (lgrp >> 1)) ^ (lid & 7);
    const int base = (lid << 6) + (chunk << 3) + ((lgrp & 1) << 2);
    *(unsigned*)&un[base]     = a;
    *(unsigned*)&un[base + 2] = b;
  }

  // O^T += V^T P^T
  __builtin_amdgcn_s_setprio(1);
  #pragma unroll
  for (int kk = 0; kk < 2; ++kk){
    const int kc = kk * 4 + lgrp;
    const bf16x8 pb = *(const bf16x8*)&un[(lid << 6) + ((kc ^ (lid & 7)) << 3)];
    #pragma unroll
    for (int n4 = 0; n4 < 4; ++n4){
      const bf16x8 vf = *(const bf16x8*)&Vsb[((n4*16 + lid) << 6) + ((kc ^ (lid & 7)) << 3)];
      o[n4] = MFMA16(vf, pb, o[n4]);
    }
  }
  __builtin_amdgcn_s_setprio(0);
}

__device__ __forceinline__ void attn_writeout(
    unsigned short* __restrict__ AO, int qrow, int h, int lgrp,
    float l_i, const f32x4 (&o)[4])
{
  const float inv = 1.f / l_i;
  unsigned short* dst = AO + (size_t)qrow * 1024 + h * 64;
  #pragma unroll
  for (int n4 = 0; n4 < 4; ++n4){
    unsigned r0 = ((unsigned)f2bf_rn(o[n4][0] * inv)) | (((unsigned)f2bf_rn(o[n4][1] * inv)) << 16);
    unsigned r1 = ((unsigned)f2bf_rn(o[n4][2] * inv)) | (((unsigned)f2bf_rn(o[n4][3] * inv)) << 16);
    unsigned long long pk = ((unsigned long long)r1 << 32) | r0;
    *(unsigned long long*)(dst + n4*16 + lgrp*4) = pk;
  }
}

__global__ __launch_bounds__(64) void attn_mfma(
    const unsigned short* __restrict__ Y,
    const unsigned short* __restrict__ Vt,
    const unsigned short* __restrict__ BndT,
    unsigned short* __restrict__ AO)
{
  __shared__ unsigned short Ks[2][64 * 64];   // [j][d] chunk-swizzled, dbuf
  __shared__ unsigned short Vs[2][64 * 64];   // [d][j] chunk-swizzled, dbuf
  __shared__ unsigned short UN[1280];         // El bf16 [16][80] / Pl [16][64] union

  const int id = blockIdx.x;
  const int h = id & 15;
  const int u = (id >> 4) & 3;               // quarter within the 64-row block
  const int p = id >> 6;                      // pair index [0,16)
  const int qbA = 31 - p, qbB = p;
  const int ntA = qbA + 1;                    // iters in segment A; total = 33
  const int lane = threadIdx.x;               // single wave
  const int lid = lane & 15, lgrp = lane >> 4;
  const int sr = lane >> 3;
  const int scc = (lane & 7) ^ sr;

  const int ql = u * 16 + lid;                // local-64 q (same both segments)
  const int qrowA = qbA * 64 + u * 16 + lid;
  const int qrowB = qbB * 64 + u * 16 + lid;

  // loop-invariant fragments, both segments
  bf16x8 qfA[2], qfB[2];
  #pragma unroll
  for (int kk = 0; kk < 2; ++kk){
    qfA[kk] = *(const bf16x8*)(Y + (size_t)qrowA * LDY2 + h*64 + ((kk*4 + lgrp) << 3));
    qfB[kk] = *(const bf16x8*)(Y + (size_t)qrowB * LDY2 + h*64 + ((kk*4 + lgrp) << 3));
  }
  bf16x8 rfA = {}, rfB = {};
  {
    const unsigned* rpA = (const unsigned*)(Y + (size_t)qrowA * LDY2 + 3072 + h*10);
    const unsigned* rpB = (const unsigned*)(Y + (size_t)qrowB * LDY2 + 3072 + h*10);
    if (lgrp == 0){
      #pragma unroll
      for (int x = 0; x < 4; ++x){
        ((unsigned*)&rfA)[x] = rpA[x];
        ((unsigned*)&rfB)[x] = rpB[x];
      }
    } else if (lgrp == 1){
      ((unsigned*)&rfA)[0] = rpA[4];
      ((unsigned*)&rfB)[0] = rpB[4];
    }
  }

  float m_i = -INFINITY, l_i = 0.f;
  f32x4 o[4] = {};

  // prologue: stage tile 0 (segment A) into buffer 0 and drain once
  stage_tile(Y, Vt, &Ks[0][0], &Vs[0][0], 0, h, sr, scc);
  asm volatile("s_waitcnt vmcnt(0)" ::: "memory");
  __builtin_amdgcn_sched_barrier(0);

  int cur = 0;
  for (int t = 0; t < 33; ++t){
    const bool segA = (t < ntA);
    const int kb = segA ? t : (t - ntA);
    const int qbX = segA ? qbA : qbB;
    const int q0w = (segA ? qbA : qbB) * 64 + u * 16;
    const int d0 = q0w - (kb << 6);

    // (1) bw loads for CURRENT tile (issued before stage so their consumption
    //     waits vmcnt(16), leaving the prefetch in flight)
    bf16x8 bw[5];
    #pragma unroll
    for (int f = 0; f < 5; ++f){
      const int rowt = d0 + 1 + f * 16 + lid;     // rel + 64
      bw[f] = *(const bf16x8*)(BndT + ((size_t)rowt << 5) + (lgrp << 3));
    }

    // (2) prefetch next tile into the other buffer
    if (t + 1 < 33){
      const int t1 = t + 1;
      const int kb1 = (t1 < ntA) ? t1 : (t1 - ntA);
      stage_tile(Y, Vt, &Ks[cur ^ 1][0], &Vs[cur ^ 1][0], kb1 << 6, h, sr, scc);
    }

    // (3) compute on current buffer
    if (segA){
      attn_tile_body(&Ks[cur][0], &Vs[cur][0], UN, bw, qfA, rfA,
                     lid, lgrp, kb == qbA, ql, m_i, l_i, o);
      if (kb == qbA){
        attn_writeout(AO, qrowA, h, lgrp, l_i, o);
        m_i = -INFINITY; l_i = 0.f;
        #pragma unroll
        for (int n4 = 0; n4 < 4; ++n4) o[n4] = (f32x4){0.f,0.f,0.f,0.f};
      }
    } else {
      attn_tile_body(&Ks[cur][0], &Vs[cur][0], UN, bw, qfB, rfB,
                     lid, lgrp, kb == qbB, ql, m_i, l_i, o);
      if (kb == qbB)
        attn_writeout(AO, qrowB, h, lgrp, l_i, o);
    }
    (void)qbX;

    // (4) drain the prefetch (hidden under the body's ~1.5k cycles)
    asm volatile("s_waitcnt vmcnt(0)" ::: "memory");
    __builtin_amdgcn_sched_barrier(0);
    cur ^= 1;
  }
}

// ---------------- launch ----------------

extern "C" void kernel_launch(void* const* d_in, const int* in_sizes, int n_in,
                              void* d_out, int out_size, void* d_ws, size_t ws_size,
                              hipStream_t stream) {
  const float* X   = (const float*)d_in[0];
  const float* Wq  = (const float*)d_in[1];
  const float* bq  = (const float*)d_in[2];
  const float* Wk  = (const float*)d_in[3];
  const float* Wv  = (const float*)d_in[4];
  const float* Wp  = (const float*)d_in[5];
  const float* bp  = (const float*)d_in[6];
  const float* Wr  = (const float*)d_in[7];
  const float* br  = (const float*)d_in[8];
  const float* bnd = (const float*)d_in[9];
  float* out = (float*)d_out;

  unsigned short* Xb  = (unsigned short*)d_ws;            // 2048*1024 (reused as AO)
  unsigned short* WbT = Xb  + (size_t)2048 * 1024;        // 3328*1024
  unsigned short* Yb  = WbT + (size_t)3328 * 1024;        // 2048*3328
  unsigned short* Vt  = Yb  + (size_t)2048 * 3328;        // 1024*2048
  unsigned short* WpT = Vt  + (size_t)1024 * 2048;        // 1024*1024
  float* bias = (float*)(WpT + (size_t)1024 * 1024);      // 3328
  unsigned short* AO   = Xb;                    // Xb dead after gemm1
  unsigned short* BndT = WbT + (size_t)3232 * 1024;  // WbT pad rows (dead after gemm1)

  prep_mega    <<<2125,         256, 0, stream>>>(X, Wq, Wk, Wv, Wr, Wp, bq, br,
                                                  Xb, WbT, WpT, bias);
  gemm_bf16    <<<dim3(26, 16), 256, 0, stream>>>(Xb, WbT, bias, Yb, 3328);
  post_mega    <<<521,          256, 0, stream>>>(Yb, bnd, Vt, BndT);
  attn_mfma    <<<1024,         64,  0, stream>>>(Yb, Vt, BndT, AO);
  gemm_bf16_out<<<dim3(8, 32),  256, 0, stream>>>(AO, WpT, bp, out);
}

// Round 15
// 110.339 us; speedup vs baseline: 1.1986x; 1.1986x over previous
//
#include <hip/hip_runtime.h>
#include <hip/hip_bf16.h>
#include <math.h>

// Problem: B=1, T=2048, E=1024, H=16, DH=64, NB=10, ML=2048
// Pipeline (all bf16 MFMA):
//   prep_mega: Xb = bf16(X); WbT = [Wq*0.125*log2e|Wk|Wv|Wr]^T; WpT; bias
//   gemm1: Y[2048][3328] = Xb @ Wb + bias   (Q|K|V|R)
//   post_mega: Vt[h][d][t] = V^T per head; BndT*log2e table (WbT pad rows)
//   attn: 1024 blocks x 128 thr; block = (h, quarter, pair p).
//         Two INDEPENDENT kv-parity wave-streams over the same 16 q-rows;
//         uniform 17 iters (qbA=31-p then qbB=p); no loop barriers;
//         exact per-segment 2-way merge in LDS. exp2-domain softmax.
//   gemm2 (64x128 tiles, 256 blocks): out = AO @ Wp + bp (f32)

typedef __attribute__((ext_vector_type(8))) short bf16x8;
typedef __attribute__((ext_vector_type(4))) float f32x4;

#define MFMA16(a,b,c) __builtin_amdgcn_mfma_f32_16x16x32_bf16((a),(b),(c),0,0,0)
#define GLB(p)  ((const __attribute__((address_space(1))) void*)(p))
#define LDSP(p) ((__attribute__((address_space(3))) void*)(p))
#define LDY2 3328
#define LOG2E 1.44269504088896f

__device__ __forceinline__ unsigned short f2bf(float x){
  unsigned u = __float_as_uint(x);
  u = (u + 0x7FFFu + ((u >> 16) & 1u)) >> 16;
  return (unsigned short)u;
}
__device__ __forceinline__ unsigned short f2bf_rn(float x){
  __hip_bfloat16 b = __float2bfloat16(x);
  return *reinterpret_cast<unsigned short*>(&b);
}
__device__ __forceinline__ float bf2f(unsigned short b){
  return __uint_as_float(((unsigned)b) << 16);
}

// ---------------- fused prep kernel (convert_x | pack_wbt | transpose_wp | bias)

__global__ __launch_bounds__(256) void prep_mega(
    const float* __restrict__ X,
    const float* __restrict__ Wq, const float* __restrict__ Wk,
    const float* __restrict__ Wv, const float* __restrict__ Wr,
    const float* __restrict__ Wp,
    const float* __restrict__ bq, const float* __restrict__ br,
    unsigned short* __restrict__ Xb, unsigned short* __restrict__ WbT,
    unsigned short* __restrict__ WpT, float* __restrict__ bias)
{
  __shared__ float tile[64][65];
  const int b = blockIdx.x;
  const int tid = threadIdx.x;

  if (b < 1024){
    const int i = (b * 256 + tid) * 8;
    f32x4 a = *(const f32x4*)(X + i);
    f32x4 v2 = *(const f32x4*)(X + i + 4);
    bf16x8 v;
    v[0]=(short)f2bf(a.x); v[1]=(short)f2bf(a.y); v[2]=(short)f2bf(a.z); v[3]=(short)f2bf(a.w);
    v[4]=(short)f2bf(v2.x); v[5]=(short)f2bf(v2.y); v[6]=(short)f2bf(v2.z); v[7]=(short)f2bf(v2.w);
    *(bf16x8*)(Xb + i) = v;
    return;
  }
  if (b < 1024 + 832){
    const int idx = b - 1024;
    const int k0 = (idx & 15) * 64, c0 = (idx >> 4) * 64;
    {
      const int r = tid >> 2, cs = (tid & 3) << 4;
      #pragma unroll
      for (int q = 0; q < 4; ++q){
        const int c = c0 + cs + q * 4;
        f32x4 v;
        if (c < 1024){
          v = *(const f32x4*)(Wq + (size_t)(k0+r)*1024 + c);
          const float s = 0.125f * LOG2E;   // fold 1/sqrt(d) and log2e into Q
          v.x *= s; v.y *= s; v.z *= s; v.w *= s;
        }
        else if (c < 2048) v = *(const f32x4*)(Wk + (size_t)(k0+r)*1024 + (c-1024));
        else if (c < 3072) v = *(const f32x4*)(Wv + (size_t)(k0+r)*1024 + (c-2048));
        else if (c < 3232) v = *(const f32x4*)(Wr + (size_t)(k0+r)*160  + (c-3072));
        else               v = (f32x4){0.f,0.f,0.f,0.f};
        tile[r][cs+q*4+0]=v.x; tile[r][cs+q*4+1]=v.y; tile[r][cs+q*4+2]=v.z; tile[r][cs+q*4+3]=v.w;
      }
    }
    __syncthreads();
    const int c = tid >> 2, ks = (tid & 3) << 4;
    bf16x8 o0, o1;
    #pragma unroll
    for (int x = 0; x < 8; ++x) o0[x] = (short)f2bf(tile[ks + x][c]);
    #pragma unroll
    for (int x = 0; x < 8; ++x) o1[x] = (short)f2bf(tile[ks + 8 + x][c]);
    *(bf16x8*)(WbT + (size_t)(c0 + c) * 1024 + k0 + ks)     = o0;
    *(bf16x8*)(WbT + (size_t)(c0 + c) * 1024 + k0 + ks + 8) = o1;
    return;
  }
  if (b < 1024 + 832 + 256){
    const int idx = b - 1856;
    const int k0 = (idx & 15) * 64, c0 = (idx >> 4) * 64;
    {
      const int r = tid >> 2, cs = (tid & 3) << 4;
      #pragma unroll
      for (int q = 0; q < 4; ++q){
        f32x4 v = *(const f32x4*)(Wp + (size_t)(k0+r)*1024 + c0 + cs + q*4);
        tile[r][cs+q*4+0]=v.x; tile[r][cs+q*4+1]=v.y; tile[r][cs+q*4+2]=v.z; tile[r][cs+q*4+3]=v.w;
      }
    }
    __syncthreads();
    const int c = tid >> 2, ks = (tid & 3) << 4;
    bf16x8 o0, o1;
    #pragma unroll
    for (int x = 0; x < 8; ++x) o0[x] = (short)f2bf(tile[ks + x][c]);
    #pragma unroll
    for (int x = 0; x < 8; ++x) o1[x] = (short)f2bf(tile[ks + 8 + x][c]);
    *(bf16x8*)(WpT + (size_t)(c0 + c) * 1024 + k0 + ks)     = o0;
    *(bf16x8*)(WpT + (size_t)(c0 + c) * 1024 + k0 + ks + 8) = o1;
    return;
  }
  const int c = (b - 2112) * 256 + tid;
  if (c < 3328){
    float v = 0.f;
    if (c < 1024) v = bq[c] * 0.125f * LOG2E;
    else if (c >= 3072 && c < 3232) v = br[c - 3072];
    bias[c] = v;
  }
}

// ---------------- fused post kernel (vt_transpose | build_bndt) --------------

__global__ __launch_bounds__(256) void post_mega(
    const unsigned short* __restrict__ Y, const float* __restrict__ bnd,
    unsigned short* __restrict__ Vt, unsigned short* __restrict__ BndT)
{
  __shared__ unsigned short tile[64][72];
  const int b = blockIdx.x;
  const int tid = threadIdx.x;

  if (b < 512){
    const int h = b >> 5, t0 = (b & 31) * 64;
    {
      const int r = tid >> 2, cs = (tid & 3) << 4;
      const unsigned short* src = Y + (size_t)(t0 + r) * LDY2 + 2048 + h * 64 + cs;
      *(bf16x8*)&tile[r][cs]     = *(const bf16x8*)src;
      *(bf16x8*)&tile[r][cs + 8] = *(const bf16x8*)(src + 8);
    }
    __syncthreads();
    const int d = tid >> 2, ts = (tid & 3) << 4;
    bf16x8 o0, o1;
    #pragma unroll
    for (int x = 0; x < 8; ++x) o0[x] = (short)tile[ts + x][d];
    #pragma unroll
    for (int x = 0; x < 8; ++x) o1[x] = (short)tile[ts + 8 + x][d];
    *(bf16x8*)(Vt + (size_t)(h*64 + d) * 2048 + t0 + ts)     = o0;
    *(bf16x8*)(Vt + (size_t)(h*64 + d) * 2048 + t0 + ts + 8) = o1;
    return;
  }
  // BndT[t'][32] scaled by log2e (E contributes to exp2-domain logits)
  const int t = (b - 512) * 256 + tid;
  if (t >= 2176) return;
  const int rel = t - 64;
  unsigned short* dst = BndT + (size_t)t * 32;
  bf16x8 v0 = {}, v1 = {}, z = {};
  if (rel >= 0 && rel < 2048){
    #pragma unroll
    for (int n = 0; n < 8; ++n) v0[n] = (short)f2bf(bnd[n * 2048 + rel] * LOG2E);
    v1[0] = (short)f2bf(bnd[8 * 2048 + rel] * LOG2E);
    v1[1] = (short)f2bf(bnd[9 * 2048 + rel] * LOG2E);
  }
  *(bf16x8*)dst        = v0;
  *(bf16x8*)(dst + 8)  = v1;
  *(bf16x8*)(dst + 16) = z;
  *(bf16x8*)(dst + 24) = z;
}

// ---------------- bf16 MFMA GEMM, 128x128 tile (projection) -----------------

__global__ __launch_bounds__(256) void gemm_bf16(
    const unsigned short* __restrict__ A,
    const unsigned short* __restrict__ BT,
    const float* __restrict__ bias,
    unsigned short* __restrict__ C, int ldc)
{
  __shared__ unsigned short As[128 * 64];
  __shared__ unsigned short Bs[128 * 64];
  const int tid = threadIdx.x;
  const int w = tid >> 6, lane = tid & 63;
  const int lid = lane & 15, lgrp = lane >> 4;
  const int wm = w >> 1, wn = w & 1;
  const int row0 = blockIdx.y << 7, col0 = blockIdx.x << 7;
  const int sr = lane >> 3;
  const int sc = (lane & 7) ^ sr;

  f32x4 acc[4][4] = {};

  for (int k0 = 0; k0 < 1024; k0 += 64){
    #pragma unroll
    for (int it = 0; it < 4; ++it){
      const int r0w = (w << 5) + (it << 3);
      const int r = r0w + sr;
      __builtin_amdgcn_global_load_lds(GLB(A  + (size_t)(row0 + r) * 1024 + k0 + (sc << 3)),
                                       LDSP(&As[r0w << 6]), 16, 0, 0);
      __builtin_amdgcn_global_load_lds(GLB(BT + (size_t)(col0 + r) * 1024 + k0 + (sc << 3)),
                                       LDSP(&Bs[r0w << 6]), 16, 0, 0);
    }
    __syncthreads();

    bf16x8 af[4][2], bfr[4][2];
    #pragma unroll
    for (int m = 0; m < 4; ++m){
      const int ra = wm * 64 + m * 16 + lid;
      const int rb = wn * 64 + m * 16 + lid;
      #pragma unroll
      for (int kk = 0; kk < 2; ++kk){
        const int kc = kk * 4 + lgrp;
        af[m][kk]  = *(const bf16x8*)&As[(ra << 6) + ((kc ^ (lid & 7)) << 3)];
        bfr[m][kk] = *(const bf16x8*)&Bs[(rb << 6) + ((kc ^ (lid & 7)) << 3)];
      }
    }
    #pragma unroll
    for (int m = 0; m < 4; ++m)
      #pragma unroll
      for (int n = 0; n < 4; ++n){
        acc[m][n] = MFMA16(af[m][0], bfr[n][0], acc[m][n]);
        acc[m][n] = MFMA16(af[m][1], bfr[n][1], acc[m][n]);
      }
    __syncthreads();
  }

  #pragma unroll
  for (int m = 0; m < 4; ++m){
    #pragma unroll
    for (int n = 0; n < 4; ++n){
      const int col = col0 + wn * 64 + n * 16 + lid;
      const float bv = bias[col];
      #pragma unroll
      for (int i = 0; i < 4; ++i){
        const int row = row0 + wm * 64 + m * 16 + lgrp * 4 + i;
        C[(size_t)row * ldc + col] = f2bf(acc[m][n][i] + bv);
      }
    }
  }
}

// ---------------- bf16 MFMA GEMM, 64x128 tile, f32 out (out-projection) -----

__global__ __launch_bounds__(256) void gemm_bf16_out(
    const unsigned short* __restrict__ A,
    const unsigned short* __restrict__ BT,
    const float* __restrict__ bias,
    float* __restrict__ C)
{
  __shared__ unsigned short As[64 * 64];
  __shared__ unsigned short Bs[128 * 64];
  const int tid = threadIdx.x;
  const int w = tid >> 6, lane = tid & 63;
  const int lid = lane & 15, lgrp = lane >> 4;
  const int wm = w >> 1, wn = w & 1;
  const int row0 = blockIdx.y << 6, col0 = blockIdx.x << 7;
  const int sr = lane >> 3;
  const int sc = (lane & 7) ^ sr;

  f32x4 acc[2][4] = {};

  for (int k0 = 0; k0 < 1024; k0 += 64){
    #pragma unroll
    for (int it = 0; it < 2; ++it){
      const int r0w = (w << 4) + (it << 3);
      const int r = r0w + sr;
      __builtin_amdgcn_global_load_lds(GLB(A + (size_t)(row0 + r) * 1024 + k0 + (sc << 3)),
                                       LDSP(&As[r0w << 6]), 16, 0, 0);
    }
    #pragma unroll
    for (int it = 0; it < 4; ++it){
      const int r0w = (w << 5) + (it << 3);
      const int r = r0w + sr;
      __builtin_amdgcn_global_load_lds(GLB(BT + (size_t)(col0 + r) * 1024 + k0 + (sc << 3)),
                                       LDSP(&Bs[r0w << 6]), 16, 0, 0);
    }
    __syncthreads();

    bf16x8 af[2][2], bfr[4][2];
    #pragma unroll
    for (int m = 0; m < 2; ++m){
      const int ra = wm * 32 + m * 16 + lid;
      #pragma unroll
      for (int kk = 0; kk < 2; ++kk){
        const int kc = kk * 4 + lgrp;
        af[m][kk] = *(const bf16x8*)&As[(ra << 6) + ((kc ^ (lid & 7)) << 3)];
      }
    }
    #pragma unroll
    for (int n = 0; n < 4; ++n){
      const int rb = wn * 64 + n * 16 + lid;
      #pragma unroll
      for (int kk = 0; kk < 2; ++kk){
        const int kc = kk * 4 + lgrp;
        bfr[n][kk] = *(const bf16x8*)&Bs[(rb << 6) + ((kc ^ (lid & 7)) << 3)];
      }
    }
    #pragma unroll
    for (int m = 0; m < 2; ++m)
      #pragma unroll
      for (int n = 0; n < 4; ++n){
        acc[m][n] = MFMA16(af[m][0], bfr[n][0], acc[m][n]);
        acc[m][n] = MFMA16(af[m][1], bfr[n][1], acc[m][n]);
      }
    __syncthreads();
  }

  #pragma unroll
  for (int m = 0; m < 2; ++m){
    #pragma unroll
    for (int n = 0; n < 4; ++n){
      const int col = col0 + wn * 64 + n * 16 + lid;
      const float bv = bias[col];
      #pragma unroll
      for (int i = 0; i < 4; ++i){
        const int row = row0 + wm * 32 + m * 16 + lgrp * 4 + i;
        C[(size_t)row * 1024 + col] = acc[m][n][i] + bv;
      }
    }
  }
}

// ---------------- fused flash attention -------------------------------------
// 1024 blocks x 128 thr. Block = (h, quarter u, pair p); the 2 waves are
// INDEPENDENT kv-parity streams (grp = wave id; tiles kb%2==grp) over the
// same 16 q-rows. Segments: qbA=31-p then qbB=p -> uniform 17 iters/wave.
// No barriers in the kv loop (per-wave buffers + vmcnt drains). Exact 2-way
// merge in LDS at each segment end. Softmax in exp2 domain.

__device__ __forceinline__ void stage_tile(
    const unsigned short* __restrict__ Y,
    const unsigned short* __restrict__ Vt,
    unsigned short* __restrict__ Ksb,
    unsigned short* __restrict__ Vsb,
    int j0, int h, int sr, int scc)
{
  #pragma unroll
  for (int st = 0; st < 8; ++st){
    const int r0w = st * 8;
    const int r = r0w + sr;
    __builtin_amdgcn_global_load_lds(
        GLB(Y + (size_t)(j0 + r) * LDY2 + 1024 + h*64 + (scc << 3)),
        LDSP(&Ksb[r0w << 6]), 16, 0, 0);
    __builtin_amdgcn_global_load_lds(
        GLB(Vt + (size_t)(h*64 + r) * 2048 + j0 + (scc << 3)),
        LDSP(&Vsb[r0w << 6]), 16, 0, 0);
  }
}

__device__ __forceinline__ void attn_tile_body(
    const unsigned short* __restrict__ Ksb,
    const unsigned short* __restrict__ Vsb,
    unsigned short* __restrict__ un,
    const bf16x8 (&bw)[5],
    const bf16x8 (&qf)[2], const bf16x8& rf,
    int lid, int lgrp,
    bool diag, int ql,
    float& m_i, float& l_i, f32x4 (&o)[4])
{
  // S^T = K Q^T : s[n4][i] = S[q=lid][j = n4*16 + lgrp*4 + i]  (exp2 domain)
  f32x4 s[4] = {};
  __builtin_amdgcn_s_setprio(1);
  #pragma unroll
  for (int kk = 0; kk < 2; ++kk){
    const int kc = kk * 4 + lgrp;
    #pragma unroll
    for (int n4 = 0; n4 < 4; ++n4){
      const bf16x8 kf = *(const bf16x8*)&Ksb[((n4*16 + lid) << 6) + ((kc ^ (lid & 7)) << 3)];
      s[n4] = MFMA16(kf, qf[kk], s[n4]);
    }
  }
  __builtin_amdgcn_s_setprio(0);

  // E window via MFMA -> bf16 el[q][c], c = f*16+lid
  #pragma unroll
  for (int f = 0; f < 5; ++f){
    f32x4 ef = {};
    ef = MFMA16(rf, bw[f], ef);
    #pragma unroll
    for (int i = 0; i < 4; ++i)
      un[(lgrp*4 + i) * 80 + f*16 + lid] = f2bf_rn(ef[i]);
  }

  // bias gather + causal mask
  #pragma unroll
  for (int n4 = 0; n4 < 4; ++n4){
    #pragma unroll
    for (int i = 0; i < 4; ++i){
      const int jl = n4*16 + lgrp*4 + i;
      float v = s[n4][i] + bf2f(un[lid * 80 + (lid - jl + 63)]);
      if (diag && jl > ql) v = -1e9f;
      s[n4][i] = v;
    }
  }

  // in-register online softmax (exp2 domain), defer-max THR = 8*log2e
  float rm = s[0][0];
  #pragma unroll
  for (int n4 = 0; n4 < 4; ++n4)
    #pragma unroll
    for (int i = 0; i < 4; ++i) rm = fmaxf(rm, s[n4][i]);
  rm = fmaxf(rm, __shfl_xor(rm, 16));
  rm = fmaxf(rm, __shfl_xor(rm, 32));

  if (__all(rm - m_i <= 11.54f)){
    float rs = 0.f;
    #pragma unroll
    for (int n4 = 0; n4 < 4; ++n4)
      #pragma unroll
      for (int i = 0; i < 4; ++i){
        const float pv = __builtin_amdgcn_exp2f(s[n4][i] - m_i);
        s[n4][i] = pv;
        rs += pv;
      }
    rs += __shfl_xor(rs, 16);
    rs += __shfl_xor(rs, 32);
    l_i += rs;
  } else {
    const float mn = fmaxf(m_i, rm);
    const float sc_ = __builtin_amdgcn_exp2f(m_i - mn);
    m_i = mn;
    float rs = 0.f;
    #pragma unroll
    for (int n4 = 0; n4 < 4; ++n4)
      #pragma unroll
      for (int i = 0; i < 4; ++i){
        const float pv = __builtin_amdgcn_exp2f(s[n4][i] - mn);
        s[n4][i] = pv;
        rs += pv;
      }
    rs += __shfl_xor(rs, 16);
    rs += __shfl_xor(rs, 32);
    l_i = l_i * sc_ + rs;
    #pragma unroll
    for (int n4 = 0; n4 < 4; ++n4)
      #pragma unroll
      for (int i = 0; i < 4; ++i) o[n4][i] *= sc_;
  }

  // P -> wave-local LDS (union region; el reads above complete first)
  #pragma unroll
  for (int n4 = 0; n4 < 4; ++n4){
    const unsigned a = ((unsigned)f2bf_rn(s[n4][0])) | (((unsigned)f2bf_rn(s[n4][1])) << 16);
    const unsigned b = ((unsigned)f2bf_rn(s[n4][2])) | (((unsigned)f2bf_rn(s[n4][3])) << 16);
    const int chunk = (n4*2 + (lgrp >> 1)) ^ (lid & 7);
    const int base = (lid << 6) + (chunk << 3) + ((lgrp & 1) << 2);
    *(unsigned*)&un[base]     = a;
    *(unsigned*)&un[base + 2] = b;
  }

  // O^T += V^T P^T
  __builtin_amdgcn_s_setprio(1);
  #pragma unroll
  for (int kk = 0; kk < 2; ++kk){
    const int kc = kk * 4 + lgrp;
    const bf16x8 pb = *(const bf16x8*)&un[(lid << 6) + ((kc ^ (lid & 7)) << 3)];
    #pragma unroll
    for (int n4 = 0; n4 < 4; ++n4){
      const bf16x8 vf = *(const bf16x8*)&Vsb[((n4*16 + lid) << 6) + ((kc ^ (lid & 7)) << 3)];
      o[n4] = MFMA16(vf, pb, o[n4]);
    }
  }
  __builtin_amdgcn_s_setprio(0);
}

__global__ __launch_bounds__(128) void attn_mfma(
    const unsigned short* __restrict__ Y,
    const unsigned short* __restrict__ Vt,
    const unsigned short* __restrict__ BndT,
    unsigned short* __restrict__ AO)
{
  __shared__ unsigned short KV[4][4096];  // K(grp0), K(grp1), V(grp0), V(grp1)
  __shared__ unsigned short UN[2][1280];  // per-wave El/Pl union

  const int id = blockIdx.x;
  const int h = id & 15;
  const int u = (id >> 4) & 3;            // quarter within the 64-row block
  const int p = id >> 6;                  // pair index [0,16)
  const int tid = threadIdx.x;
  const int grp = tid >> 6;               // kv-parity stream (wave id)
  const int lane = tid & 63;
  const int lid = lane & 15, lgrp = lane >> 4;
  const int sr = lane >> 3;
  const int scc = (lane & 7) ^ sr;

  unsigned short* Ksg = &KV[grp][0];
  unsigned short* Vsg = &KV[2 + grp][0];
  unsigned short* un  = &UN[grp][0];

  const int ql = u * 16 + lid;            // local-64 q (same both segments)

  #pragma unroll
  for (int seg = 0; seg < 2; ++seg){
    const int qb = seg ? (id >> 6) : (31 - (id >> 6));   // qbA=31-p, qbB=p
    const int q0w = qb * 64 + u * 16;
    const int qrow = q0w + lid;
    const int nt = qb + 1;
    const int L = (nt + 1) >> 1;

    // loop-invariant fragments for this segment
    bf16x8 qf[2];
    #pragma unroll
    for (int kk = 0; kk < 2; ++kk)
      qf[kk] = *(const bf16x8*)(Y + (size_t)qrow * LDY2 + h*64 + ((kk*4 + lgrp) << 3));
    bf16x8 rf = {};
    {
      const unsigned* rp = (const unsigned*)(Y + (size_t)qrow * LDY2 + 3072 + h*10);
      if (lgrp == 0){
        #pragma unroll
        for (int x = 0; x < 4; ++x) ((unsigned*)&rf)[x] = rp[x];
      } else if (lgrp == 1){
        ((unsigned*)&rf)[0] = rp[4];
      }
    }

    float m_i = -INFINITY, l_i = 0.f;
    f32x4 o[4] = {};

    // independent per-wave kv stream: tiles kb = grp, grp+2, ...
    for (int it = 0; it < L; ++it){
      const int kb = 2 * it + grp;
      if (kb < nt){
        const int j0 = kb << 6;
        const int d0 = q0w - j0;

        stage_tile(Y, Vt, Ksg, Vsg, j0, h, sr, scc);

        bf16x8 bw[5];
        #pragma unroll
        for (int f = 0; f < 5; ++f){
          const int rowt = d0 + 1 + f * 16 + lid;     // rel + 64
          bw[f] = *(const bf16x8*)(BndT + ((size_t)rowt << 5) + (lgrp << 3));
        }

        asm volatile("s_waitcnt vmcnt(0)" ::: "memory");
        __builtin_amdgcn_sched_barrier(0);

        attn_tile_body(Ksg, Vsg, un, bw, qf, rf, lid, lgrp,
                       kb == qb, ql, m_i, l_i, o);
      }
    }

    // ---- exact 2-way merge of the parity streams (in LDS) ----
    float* oScr  = (float*)&KV[1][0];     // 16 q x 64 d f32 (4 KB, grp1's K buf)
    float* mlScr = (float*)&KV[3][0];     // 16 q x 2 f32 (grp1's V buf)
    if (grp == 1){
      #pragma unroll
      for (int n4 = 0; n4 < 4; ++n4)
        *(f32x4*)&oScr[lid * 64 + n4*16 + lgrp*4] = o[n4];
      if (lgrp == 0){
        mlScr[lid * 2 + 0] = m_i;
        mlScr[lid * 2 + 1] = l_i;
      }
    }
    __syncthreads();
    if (grp == 0){
      const float m1 = mlScr[lid * 2 + 0];
      const float l1 = mlScr[lid * 2 + 1];
      const float M  = fmaxf(m_i, m1);
      const float a  = __builtin_amdgcn_exp2f(m_i - M);
      const float b  = __builtin_amdgcn_exp2f(m1 - M);
      const float inv = 1.f / (l_i * a + l1 * b);
      unsigned short* dst = AO + (size_t)qrow * 1024 + h * 64;
      #pragma unroll
      for (int n4 = 0; n4 < 4; ++n4){
        const f32x4 o1 = *(const f32x4*)&oScr[lid * 64 + n4*16 + lgrp*4];
        const float v0 = (o[n4][0]*a + o1[0]*b) * inv;
        const float v1 = (o[n4][1]*a + o1[1]*b) * inv;
        const float v2 = (o[n4][2]*a + o1[2]*b) * inv;
        const float v3 = (o[n4][3]*a + o1[3]*b) * inv;
        unsigned r0 = ((unsigned)f2bf_rn(v0)) | (((unsigned)f2bf_rn(v1)) << 16);
        unsigned r1 = ((unsigned)f2bf_rn(v2)) | (((unsigned)f2bf_rn(v3)) << 16);
        unsigned long long pk = ((unsigned long long)r1 << 32) | r0;
        *(unsigned long long*)(dst + n4*16 + lgrp*4) = pk;
      }
    }
    __syncthreads();   // scratch (KV[1]/KV[3]) free before next segment staging
  }
}

// ---------------- launch ----------------

extern "C" void kernel_launch(void* const* d_in, const int* in_sizes, int n_in,
                              void* d_out, int out_size, void* d_ws, size_t ws_size,
                              hipStream_t stream) {
  const float* X   = (const float*)d_in[0];
  const float* Wq  = (const float*)d_in[1];
  const float* bq  = (const float*)d_in[2];
  const float* Wk  = (const float*)d_in[3];
  const float* Wv  = (const float*)d_in[4];
  const float* Wp  = (const float*)d_in[5];
  const float* bp  = (const float*)d_in[6];
  const float* Wr  = (const float*)d_in[7];
  const float* br  = (const float*)d_in[8];
  const float* bnd = (const float*)d_in[9];
  float* out = (float*)d_out;

  unsigned short* Xb  = (unsigned short*)d_ws;            // 2048*1024 (reused as AO)
  unsigned short* WbT = Xb  + (size_t)2048 * 1024;        // 3328*1024
  unsigned short* Yb  = WbT + (size_t)3328 * 1024;        // 2048*3328
  unsigned short* Vt  = Yb  + (size_t)2048 * 3328;        // 1024*2048
  unsigned short* WpT = Vt  + (size_t)1024 * 2048;        // 1024*1024
  float* bias = (float*)(WpT + (size_t)1024 * 1024);      // 3328
  unsigned short* AO   = Xb;                    // Xb dead after gemm1
  unsigned short* BndT = WbT + (size_t)3232 * 1024;  // WbT pad rows (dead after gemm1)

  prep_mega    <<<2125,         256, 0, stream>>>(X, Wq, Wk, Wv, Wr, Wp, bq, br,
                                                  Xb, WbT, WpT, bias);
  gemm_bf16    <<<dim3(26, 16), 256, 0, stream>>>(Xb, WbT, bias, Yb, 3328);
  post_mega    <<<521,          256, 0, stream>>>(Yb, bnd, Vt, BndT);
  attn_mfma    <<<1024,         128, 0, stream>>>(Yb, Vt, BndT, AO);
  gemm_bf16_out<<<dim3(8, 32),  256, 0, stream>>>(AO, WpT, bp, out);
}

// Round 16
// 107.839 us; speedup vs baseline: 1.2264x; 1.0232x over previous
//
#include <hip/hip_runtime.h>
#include <hip/hip_bf16.h>
#include <math.h>

// Problem: B=1, T=2048, E=1024, H=16, DH=64, NB=10, ML=2048
// Pipeline (all bf16 MFMA):
//   prep_mega: Xb = bf16(X); WbT = [Wq*0.125*log2e|Wk|Wv|Wr]^T; WpT; bias
//   gemm64 (64x128 tiles, 832 blocks): Y = Xb @ Wb + bias  (Q|K|V|R)
//   post_mega: Vt[h][d][t] = V^T per head; BndT*log2e table (WbT pad rows)
//   attn: r15 structure (frozen at ~59us): 1024 blocks x 128 thr, independent
//         kv-parity wave-streams, uniform 17 iters, exp2-domain softmax
//   gemm64 (64x128 tiles, 256 blocks): out = AO @ Wp + bp (f32)

typedef __attribute__((ext_vector_type(8))) short bf16x8;
typedef __attribute__((ext_vector_type(4))) float f32x4;

#define MFMA16(a,b,c) __builtin_amdgcn_mfma_f32_16x16x32_bf16((a),(b),(c),0,0,0)
#define GLB(p)  ((const __attribute__((address_space(1))) void*)(p))
#define LDSP(p) ((__attribute__((address_space(3))) void*)(p))
#define LDY2 3328
#define LOG2E 1.44269504088896f

__device__ __forceinline__ unsigned short f2bf(float x){
  unsigned u = __float_as_uint(x);
  u = (u + 0x7FFFu + ((u >> 16) & 1u)) >> 16;
  return (unsigned short)u;
}
__device__ __forceinline__ unsigned short f2bf_rn(float x){
  __hip_bfloat16 b = __float2bfloat16(x);
  return *reinterpret_cast<unsigned short*>(&b);
}
__device__ __forceinline__ float bf2f(unsigned short b){
  return __uint_as_float(((unsigned)b) << 16);
}

// ---------------- fused prep kernel (convert_x | pack_wbt | transpose_wp | bias)

__global__ __launch_bounds__(256) void prep_mega(
    const float* __restrict__ X,
    const float* __restrict__ Wq, const float* __restrict__ Wk,
    const float* __restrict__ Wv, const float* __restrict__ Wr,
    const float* __restrict__ Wp,
    const float* __restrict__ bq, const float* __restrict__ br,
    unsigned short* __restrict__ Xb, unsigned short* __restrict__ WbT,
    unsigned short* __restrict__ WpT, float* __restrict__ bias)
{
  __shared__ float tile[64][65];
  const int b = blockIdx.x;
  const int tid = threadIdx.x;

  if (b < 1024){
    const int i = (b * 256 + tid) * 8;
    f32x4 a = *(const f32x4*)(X + i);
    f32x4 v2 = *(const f32x4*)(X + i + 4);
    bf16x8 v;
    v[0]=(short)f2bf(a.x); v[1]=(short)f2bf(a.y); v[2]=(short)f2bf(a.z); v[3]=(short)f2bf(a.w);
    v[4]=(short)f2bf(v2.x); v[5]=(short)f2bf(v2.y); v[6]=(short)f2bf(v2.z); v[7]=(short)f2bf(v2.w);
    *(bf16x8*)(Xb + i) = v;
    return;
  }
  if (b < 1024 + 832){
    const int idx = b - 1024;
    const int k0 = (idx & 15) * 64, c0 = (idx >> 4) * 64;
    {
      const int r = tid >> 2, cs = (tid & 3) << 4;
      #pragma unroll
      for (int q = 0; q < 4; ++q){
        const int c = c0 + cs + q * 4;
        f32x4 v;
        if (c < 1024){
          v = *(const f32x4*)(Wq + (size_t)(k0+r)*1024 + c);
          const float s = 0.125f * LOG2E;   // fold 1/sqrt(d) and log2e into Q
          v.x *= s; v.y *= s; v.z *= s; v.w *= s;
        }
        else if (c < 2048) v = *(const f32x4*)(Wk + (size_t)(k0+r)*1024 + (c-1024));
        else if (c < 3072) v = *(const f32x4*)(Wv + (size_t)(k0+r)*1024 + (c-2048));
        else if (c < 3232) v = *(const f32x4*)(Wr + (size_t)(k0+r)*160  + (c-3072));
        else               v = (f32x4){0.f,0.f,0.f,0.f};
        tile[r][cs+q*4+0]=v.x; tile[r][cs+q*4+1]=v.y; tile[r][cs+q*4+2]=v.z; tile[r][cs+q*4+3]=v.w;
      }
    }
    __syncthreads();
    const int c = tid >> 2, ks = (tid & 3) << 4;
    bf16x8 o0, o1;
    #pragma unroll
    for (int x = 0; x < 8; ++x) o0[x] = (short)f2bf(tile[ks + x][c]);
    #pragma unroll
    for (int x = 0; x < 8; ++x) o1[x] = (short)f2bf(tile[ks + 8 + x][c]);
    *(bf16x8*)(WbT + (size_t)(c0 + c) * 1024 + k0 + ks)     = o0;
    *(bf16x8*)(WbT + (size_t)(c0 + c) * 1024 + k0 + ks + 8) = o1;
    return;
  }
  if (b < 1024 + 832 + 256){
    const int idx = b - 1856;
    const int k0 = (idx & 15) * 64, c0 = (idx >> 4) * 64;
    {
      const int r = tid >> 2, cs = (tid & 3) << 4;
      #pragma unroll
      for (int q = 0; q < 4; ++q){
        f32x4 v = *(const f32x4*)(Wp + (size_t)(k0+r)*1024 + c0 + cs + q*4);
        tile[r][cs+q*4+0]=v.x; tile[r][cs+q*4+1]=v.y; tile[r][cs+q*4+2]=v.z; tile[r][cs+q*4+3]=v.w;
      }
    }
    __syncthreads();
    const int c = tid >> 2, ks = (tid & 3) << 4;
    bf16x8 o0, o1;
    #pragma unroll
    for (int x = 0; x < 8; ++x) o0[x] = (short)f2bf(tile[ks + x][c]);
    #pragma unroll
    for (int x = 0; x < 8; ++x) o1[x] = (short)f2bf(tile[ks + 8 + x][c]);
    *(bf16x8*)(WpT + (size_t)(c0 + c) * 1024 + k0 + ks)     = o0;
    *(bf16x8*)(WpT + (size_t)(c0 + c) * 1024 + k0 + ks + 8) = o1;
    return;
  }
  const int c = (b - 2112) * 256 + tid;
  if (c < 3328){
    float v = 0.f;
    if (c < 1024) v = bq[c] * 0.125f * LOG2E;
    else if (c >= 3072 && c < 3232) v = br[c - 3072];
    bias[c] = v;
  }
}

// ---------------- fused post kernel (vt_transpose | build_bndt) --------------

__global__ __launch_bounds__(256) void post_mega(
    const unsigned short* __restrict__ Y, const float* __restrict__ bnd,
    unsigned short* __restrict__ Vt, unsigned short* __restrict__ BndT)
{
  __shared__ unsigned short tile[64][72];
  const int b = blockIdx.x;
  const int tid = threadIdx.x;

  if (b < 512){
    const int h = b >> 5, t0 = (b & 31) * 64;
    {
      const int r = tid >> 2, cs = (tid & 3) << 4;
      const unsigned short* src = Y + (size_t)(t0 + r) * LDY2 + 2048 + h * 64 + cs;
      *(bf16x8*)&tile[r][cs]     = *(const bf16x8*)src;
      *(bf16x8*)&tile[r][cs + 8] = *(const bf16x8*)(src + 8);
    }
    __syncthreads();
    const int d = tid >> 2, ts = (tid & 3) << 4;
    bf16x8 o0, o1;
    #pragma unroll
    for (int x = 0; x < 8; ++x) o0[x] = (short)tile[ts + x][d];
    #pragma unroll
    for (int x = 0; x < 8; ++x) o1[x] = (short)tile[ts + 8 + x][d];
    *(bf16x8*)(Vt + (size_t)(h*64 + d) * 2048 + t0 + ts)     = o0;
    *(bf16x8*)(Vt + (size_t)(h*64 + d) * 2048 + t0 + ts + 8) = o1;
    return;
  }
  // BndT[t'][32] scaled by log2e (E contributes to exp2-domain logits)
  const int t = (b - 512) * 256 + tid;
  if (t >= 2176) return;
  const int rel = t - 64;
  unsigned short* dst = BndT + (size_t)t * 32;
  bf16x8 v0 = {}, v1 = {}, z = {};
  if (rel >= 0 && rel < 2048){
    #pragma unroll
    for (int n = 0; n < 8; ++n) v0[n] = (short)f2bf(bnd[n * 2048 + rel] * LOG2E);
    v1[0] = (short)f2bf(bnd[8 * 2048 + rel] * LOG2E);
    v1[1] = (short)f2bf(bnd[9 * 2048 + rel] * LOG2E);
  }
  *(bf16x8*)dst        = v0;
  *(bf16x8*)(dst + 8)  = v1;
  *(bf16x8*)(dst + 16) = z;
  *(bf16x8*)(dst + 24) = z;
}

// ---------------- bf16 MFMA GEMM, 64x128 tile (unified) ---------------------
// C[M][N] = A[M][1024] @ BT[N][1024]^T + bias; out_f32 selects f32/bf16 store.

__global__ __launch_bounds__(256) void gemm64(
    const unsigned short* __restrict__ A,
    const unsigned short* __restrict__ BT,
    const float* __restrict__ bias,
    void* __restrict__ C, int ldc, int out_f32)
{
  __shared__ unsigned short As[64 * 64];
  __shared__ unsigned short Bs[128 * 64];
  const int tid = threadIdx.x;
  const int w = tid >> 6, lane = tid & 63;
  const int lid = lane & 15, lgrp = lane >> 4;
  const int wm = w >> 1, wn = w & 1;
  const int row0 = blockIdx.y << 6, col0 = blockIdx.x << 7;
  const int sr = lane >> 3;
  const int sc = (lane & 7) ^ sr;

  f32x4 acc[2][4] = {};

  for (int k0 = 0; k0 < 1024; k0 += 64){
    #pragma unroll
    for (int it = 0; it < 2; ++it){
      const int r0w = (w << 4) + (it << 3);
      const int r = r0w + sr;
      __builtin_amdgcn_global_load_lds(GLB(A + (size_t)(row0 + r) * 1024 + k0 + (sc << 3)),
                                       LDSP(&As[r0w << 6]), 16, 0, 0);
    }
    #pragma unroll
    for (int it = 0; it < 4; ++it){
      const int r0w = (w << 5) + (it << 3);
      const int r = r0w + sr;
      __builtin_amdgcn_global_load_lds(GLB(BT + (size_t)(col0 + r) * 1024 + k0 + (sc << 3)),
                                       LDSP(&Bs[r0w << 6]), 16, 0, 0);
    }
    __syncthreads();

    bf16x8 af[2][2], bfr[4][2];
    #pragma unroll
    for (int m = 0; m < 2; ++m){
      const int ra = wm * 32 + m * 16 + lid;
      #pragma unroll
      for (int kk = 0; kk < 2; ++kk){
        const int kc = kk * 4 + lgrp;
        af[m][kk] = *(const bf16x8*)&As[(ra << 6) + ((kc ^ (lid & 7)) << 3)];
      }
    }
    #pragma unroll
    for (int n = 0; n < 4; ++n){
      const int rb = wn * 64 + n * 16 + lid;
      #pragma unroll
      for (int kk = 0; kk < 2; ++kk){
        const int kc = kk * 4 + lgrp;
        bfr[n][kk] = *(const bf16x8*)&Bs[(rb << 6) + ((kc ^ (lid & 7)) << 3)];
      }
    }
    #pragma unroll
    for (int m = 0; m < 2; ++m)
      #pragma unroll
      for (int n = 0; n < 4; ++n){
        acc[m][n] = MFMA16(af[m][0], bfr[n][0], acc[m][n]);
        acc[m][n] = MFMA16(af[m][1], bfr[n][1], acc[m][n]);
      }
    __syncthreads();
  }

  #pragma unroll
  for (int m = 0; m < 2; ++m){
    #pragma unroll
    for (int n = 0; n < 4; ++n){
      const int col = col0 + wn * 64 + n * 16 + lid;
      const float bv = bias[col];
      #pragma unroll
      for (int i = 0; i < 4; ++i){
        const int row = row0 + wm * 32 + m * 16 + lgrp * 4 + i;
        const float v = acc[m][n][i] + bv;
        if (out_f32) ((float*)C)[(size_t)row * ldc + col] = v;
        else ((unsigned short*)C)[(size_t)row * ldc + col] = f2bf(v);
      }
    }
  }
}

// ---------------- fused flash attention (r15 structure, frozen) --------------

__device__ __forceinline__ void stage_tile(
    const unsigned short* __restrict__ Y,
    const unsigned short* __restrict__ Vt,
    unsigned short* __restrict__ Ksb,
    unsigned short* __restrict__ Vsb,
    int j0, int h, int sr, int scc)
{
  #pragma unroll
  for (int st = 0; st < 8; ++st){
    const int r0w = st * 8;
    const int r = r0w + sr;
    __builtin_amdgcn_global_load_lds(
        GLB(Y + (size_t)(j0 + r) * LDY2 + 1024 + h*64 + (scc << 3)),
        LDSP(&Ksb[r0w << 6]), 16, 0, 0);
    __builtin_amdgcn_global_load_lds(
        GLB(Vt + (size_t)(h*64 + r) * 2048 + j0 + (scc << 3)),
        LDSP(&Vsb[r0w << 6]), 16, 0, 0);
  }
}

__device__ __forceinline__ void attn_tile_body(
    const unsigned short* __restrict__ Ksb,
    const unsigned short* __restrict__ Vsb,
    unsigned short* __restrict__ un,
    const bf16x8 (&bw)[5],
    const bf16x8 (&qf)[2], const bf16x8& rf,
    int lid, int lgrp,
    bool diag, int ql,
    float& m_i, float& l_i, f32x4 (&o)[4])
{
  // S^T = K Q^T : s[n4][i] = S[q=lid][j = n4*16 + lgrp*4 + i]  (exp2 domain)
  f32x4 s[4] = {};
  __builtin_amdgcn_s_setprio(1);
  #pragma unroll
  for (int kk = 0; kk < 2; ++kk){
    const int kc = kk * 4 + lgrp;
    #pragma unroll
    for (int n4 = 0; n4 < 4; ++n4){
      const bf16x8 kf = *(const bf16x8*)&Ksb[((n4*16 + lid) << 6) + ((kc ^ (lid & 7)) << 3)];
      s[n4] = MFMA16(kf, qf[kk], s[n4]);
    }
  }
  __builtin_amdgcn_s_setprio(0);

  // E window via MFMA -> bf16 el[q][c], c = f*16+lid
  #pragma unroll
  for (int f = 0; f < 5; ++f){
    f32x4 ef = {};
    ef = MFMA16(rf, bw[f], ef);
    #pragma unroll
    for (int i = 0; i < 4; ++i)
      un[(lgrp*4 + i) * 80 + f*16 + lid] = f2bf_rn(ef[i]);
  }

  // bias gather + causal mask
  #pragma unroll
  for (int n4 = 0; n4 < 4; ++n4){
    #pragma unroll
    for (int i = 0; i < 4; ++i){
      const int jl = n4*16 + lgrp*4 + i;
      float v = s[n4][i] + bf2f(un[lid * 80 + (lid - jl + 63)]);
      if (diag && jl > ql) v = -1e9f;
      s[n4][i] = v;
    }
  }

  // in-register online softmax (exp2 domain), defer-max THR = 8*log2e
  float rm = s[0][0];
  #pragma unroll
  for (int n4 = 0; n4 < 4; ++n4)
    #pragma unroll
    for (int i = 0; i < 4; ++i) rm = fmaxf(rm, s[n4][i]);
  rm = fmaxf(rm, __shfl_xor(rm, 16));
  rm = fmaxf(rm, __shfl_xor(rm, 32));

  if (__all(rm - m_i <= 11.54f)){
    float rs = 0.f;
    #pragma unroll
    for (int n4 = 0; n4 < 4; ++n4)
      #pragma unroll
      for (int i = 0; i < 4; ++i){
        const float pv = __builtin_amdgcn_exp2f(s[n4][i] - m_i);
        s[n4][i] = pv;
        rs += pv;
      }
    rs += __shfl_xor(rs, 16);
    rs += __shfl_xor(rs, 32);
    l_i += rs;
  } else {
    const float mn = fmaxf(m_i, rm);
    const float sc_ = __builtin_amdgcn_exp2f(m_i - mn);
    m_i = mn;
    float rs = 0.f;
    #pragma unroll
    for (int n4 = 0; n4 < 4; ++n4)
      #pragma unroll
      for (int i = 0; i < 4; ++i){
        const float pv = __builtin_amdgcn_exp2f(s[n4][i] - mn);
        s[n4][i] = pv;
        rs += pv;
      }
    rs += __shfl_xor(rs, 16);
    rs += __shfl_xor(rs, 32);
    l_i = l_i * sc_ + rs;
    #pragma unroll
    for (int n4 = 0; n4 < 4; ++n4)
      #pragma unroll
      for (int i = 0; i < 4; ++i) o[n4][i] *= sc_;
  }

  // P -> wave-local LDS (union region; el reads above complete first)
  #pragma unroll
  for (int n4 = 0; n4 < 4; ++n4){
    const unsigned a = ((unsigned)f2bf_rn(s[n4][0])) | (((unsigned)f2bf_rn(s[n4][1])) << 16);
    const unsigned b = ((unsigned)f2bf_rn(s[n4][2])) | (((unsigned)f2bf_rn(s[n4][3])) << 16);
    const int chunk = (n4*2 + (lgrp >> 1)) ^ (lid & 7);
    const int base = (lid << 6) + (chunk << 3) + ((lgrp & 1) << 2);
    *(unsigned*)&un[base]     = a;
    *(unsigned*)&un[base + 2] = b;
  }

  // O^T += V^T P^T
  __builtin_amdgcn_s_setprio(1);
  #pragma unroll
  for (int kk = 0; kk < 2; ++kk){
    const int kc = kk * 4 + lgrp;
    const bf16x8 pb = *(const bf16x8*)&un[(lid << 6) + ((kc ^ (lid & 7)) << 3)];
    #pragma unroll
    for (int n4 = 0; n4 < 4; ++n4){
      const bf16x8 vf = *(const bf16x8*)&Vsb[((n4*16 + lid) << 6) + ((kc ^ (lid & 7)) << 3)];
      o[n4] = MFMA16(vf, pb, o[n4]);
    }
  }
  __builtin_amdgcn_s_setprio(0);
}

__global__ __launch_bounds__(128) void attn_mfma(
    const unsigned short* __restrict__ Y,
    const unsigned short* __restrict__ Vt,
    const unsigned short* __restrict__ BndT,
    unsigned short* __restrict__ AO)
{
  __shared__ unsigned short KV[4][4096];  // K(grp0), K(grp1), V(grp0), V(grp1)
  __shared__ unsigned short UN[2][1280];  // per-wave El/Pl union

  const int id = blockIdx.x;
  const int h = id & 15;
  const int u = (id >> 4) & 3;            // quarter within the 64-row block
  const int tid = threadIdx.x;
  const int grp = tid >> 6;               // kv-parity stream (wave id)
  const int lane = tid & 63;
  const int lid = lane & 15, lgrp = lane >> 4;
  const int sr = lane >> 3;
  const int scc = (lane & 7) ^ sr;

  unsigned short* Ksg = &KV[grp][0];
  unsigned short* Vsg = &KV[2 + grp][0];
  unsigned short* un  = &UN[grp][0];

  const int ql = u * 16 + lid;            // local-64 q (same both segments)

  #pragma unroll
  for (int seg = 0; seg < 2; ++seg){
    const int qb = seg ? (id >> 6) : (31 - (id >> 6));   // qbA=31-p, qbB=p
    const int q0w = qb * 64 + u * 16;
    const int qrow = q0w + lid;
    const int nt = qb + 1;
    const int L = (nt + 1) >> 1;

    // loop-invariant fragments for this segment
    bf16x8 qf[2];
    #pragma unroll
    for (int kk = 0; kk < 2; ++kk)
      qf[kk] = *(const bf16x8*)(Y + (size_t)qrow * LDY2 + h*64 + ((kk*4 + lgrp) << 3));
    bf16x8 rf = {};
    {
      const unsigned* rp = (const unsigned*)(Y + (size_t)qrow * LDY2 + 3072 + h*10);
      if (lgrp == 0){
        #pragma unroll
        for (int x = 0; x < 4; ++x) ((unsigned*)&rf)[x] = rp[x];
      } else if (lgrp == 1){
        ((unsigned*)&rf)[0] = rp[4];
      }
    }

    float m_i = -INFINITY, l_i = 0.f;
    f32x4 o[4] = {};

    // independent per-wave kv stream: tiles kb = grp, grp+2, ...
    for (int it = 0; it < L; ++it){
      const int kb = 2 * it + grp;
      if (kb < nt){
        const int j0 = kb << 6;
        const int d0 = q0w - j0;

        stage_tile(Y, Vt, Ksg, Vsg, j0, h, sr, scc);

        bf16x8 bw[5];
        #pragma unroll
        for (int f = 0; f < 5; ++f){
          const int rowt = d0 + 1 + f * 16 + lid;     // rel + 64
          bw[f] = *(const bf16x8*)(BndT + ((size_t)rowt << 5) + (lgrp << 3));
        }

        asm volatile("s_waitcnt vmcnt(0)" ::: "memory");
        __builtin_amdgcn_sched_barrier(0);

        attn_tile_body(Ksg, Vsg, un, bw, qf, rf, lid, lgrp,
                       kb == qb, ql, m_i, l_i, o);
      }
    }

    // ---- exact 2-way merge of the parity streams (in LDS) ----
    float* oScr  = (float*)&KV[1][0];     // 16 q x 64 d f32 (grp1's K buf)
    float* mlScr = (float*)&KV[3][0];     // 16 q x 2 f32 (grp1's V buf)
    if (grp == 1){
      #pragma unroll
      for (int n4 = 0; n4 < 4; ++n4)
        *(f32x4*)&oScr[lid * 64 + n4*16 + lgrp*4] = o[n4];
      if (lgrp == 0){
        mlScr[lid * 2 + 0] = m_i;
        mlScr[lid * 2 + 1] = l_i;
      }
    }
    __syncthreads();
    if (grp == 0){
      const float m1 = mlScr[lid * 2 + 0];
      const float l1 = mlScr[lid * 2 + 1];
      const float M  = fmaxf(m_i, m1);
      const float a  = __builtin_amdgcn_exp2f(m_i - M);
      const float b  = __builtin_amdgcn_exp2f(m1 - M);
      const float inv = 1.f / (l_i * a + l1 * b);
      unsigned short* dst = AO + (size_t)qrow * 1024 + h * 64;
      #pragma unroll
      for (int n4 = 0; n4 < 4; ++n4){
        const f32x4 o1 = *(const f32x4*)&oScr[lid * 64 + n4*16 + lgrp*4];
        const float v0 = (o[n4][0]*a + o1[0]*b) * inv;
        const float v1 = (o[n4][1]*a + o1[1]*b) * inv;
        const float v2 = (o[n4][2]*a + o1[2]*b) * inv;
        const float v3 = (o[n4][3]*a + o1[3]*b) * inv;
        unsigned r0 = ((unsigned)f2bf_rn(v0)) | (((unsigned)f2bf_rn(v1)) << 16);
        unsigned r1 = ((unsigned)f2bf_rn(v2)) | (((unsigned)f2bf_rn(v3)) << 16);
        unsigned long long pk = ((unsigned long long)r1 << 32) | r0;
        *(unsigned long long*)(dst + n4*16 + lgrp*4) = pk;
      }
    }
    __syncthreads();   // scratch (KV[1]/KV[3]) free before next segment staging
  }
}

// ---------------- launch ----------------

extern "C" void kernel_launch(void* const* d_in, const int* in_sizes, int n_in,
                              void* d_out, int out_size, void* d_ws, size_t ws_size,
                              hipStream_t stream) {
  const float* X   = (const float*)d_in[0];
  const float* Wq  = (const float*)d_in[1];
  const float* bq  = (const float*)d_in[2];
  const float* Wk  = (const float*)d_in[3];
  const float* Wv  = (const float*)d_in[4];
  const float* Wp  = (const float*)d_in[5];
  const float* bp  = (const float*)d_in[6];
  const float* Wr  = (const float*)d_in[7];
  const float* br  = (const float*)d_in[8];
  const float* bnd = (const float*)d_in[9];
  float* out = (float*)d_out;

  unsigned short* Xb  = (unsigned short*)d_ws;            // 2048*1024 (reused as AO)
  unsigned short* WbT = Xb  + (size_t)2048 * 1024;        // 3328*1024
  unsigned short* Yb  = WbT + (size_t)3328 * 1024;        // 2048*3328
  unsigned short* Vt  = Yb  + (size_t)2048 * 3328;        // 1024*2048
  unsigned short* WpT = Vt  + (size_t)1024 * 2048;        // 1024*1024
  float* bias = (float*)(WpT + (size_t)1024 * 1024);      // 3328
  unsigned short* AO   = Xb;                    // Xb dead after gemm1
  unsigned short* BndT = WbT + (size_t)3232 * 1024;  // WbT pad rows (dead after gemm1)

  prep_mega <<<2125,         256, 0, stream>>>(X, Wq, Wk, Wv, Wr, Wp, bq, br,
                                               Xb, WbT, WpT, bias);
  gemm64    <<<dim3(26, 32), 256, 0, stream>>>(Xb, WbT, bias, Yb, 3328, 0);
  post_mega <<<521,          256, 0, stream>>>(Yb, bnd, Vt, BndT);
  attn_mfma <<<1024,         128, 0, stream>>>(Yb, Vt, BndT, AO);
  gemm64    <<<dim3(8, 32),  256, 0, stream>>>(AO, WpT, bp, out, 1024, 1);
}

// Round 18
// 100.204 us; speedup vs baseline: 1.3199x; 1.0762x over previous
//
#include <hip/hip_runtime.h>
#include <hip/hip_bf16.h>
#include <math.h>

// Problem: B=1, T=2048, E=1024, H=16, DH=64, NB=10, ML=2048
// Pipeline (all bf16 MFMA):
//   prep_mega: Xb = bf16(X); WbT = [Wq*0.125*log2e|Wk|Wv|Wr]^T; WpT; bias
//   gemm64 (64x128 tiles, 832 blocks): Y = Xb @ Wb + bias  (Q|K|V|R)
//   post_mega: Vt[h][d][t] = V^T per head; BndT*log2e table (WbT pad rows)
//   attn: r15 schedule (independent kv-parity wave-streams, uniform 17 iters);
//         E-scratch [c][20] with b64-packed MAY_ALIAS writes (fixes r17 TBAA NaN)
//   gemm64 (64x128 tiles, 256 blocks): out = AO @ Wp + bp (f32)

typedef __attribute__((ext_vector_type(8))) short bf16x8;
typedef __attribute__((ext_vector_type(4))) float f32x4;
typedef unsigned long long __attribute__((may_alias)) u64a;

#define MFMA16(a,b,c) __builtin_amdgcn_mfma_f32_16x16x32_bf16((a),(b),(c),0,0,0)
#define GLB(p)  ((const __attribute__((address_space(1))) void*)(p))
#define LDSP(p) ((__attribute__((address_space(3))) void*)(p))
#define LDY2 3328
#define LOG2E 1.44269504088896f

__device__ __forceinline__ unsigned short f2bf(float x){
  unsigned u = __float_as_uint(x);
  u = (u + 0x7FFFu + ((u >> 16) & 1u)) >> 16;
  return (unsigned short)u;
}
__device__ __forceinline__ unsigned short f2bf_rn(float x){
  __hip_bfloat16 b = __float2bfloat16(x);
  return *reinterpret_cast<unsigned short*>(&b);
}
__device__ __forceinline__ float bf2f(unsigned short b){
  return __uint_as_float(((unsigned)b) << 16);
}

// ---------------- fused prep kernel (convert_x | pack_wbt | transpose_wp | bias)

__global__ __launch_bounds__(256) void prep_mega(
    const float* __restrict__ X,
    const float* __restrict__ Wq, const float* __restrict__ Wk,
    const float* __restrict__ Wv, const float* __restrict__ Wr,
    const float* __restrict__ Wp,
    const float* __restrict__ bq, const float* __restrict__ br,
    unsigned short* __restrict__ Xb, unsigned short* __restrict__ WbT,
    unsigned short* __restrict__ WpT, float* __restrict__ bias)
{
  __shared__ float tile[64][65];
  const int b = blockIdx.x;
  const int tid = threadIdx.x;

  if (b < 1024){
    const int i = (b * 256 + tid) * 8;
    f32x4 a = *(const f32x4*)(X + i);
    f32x4 v2 = *(const f32x4*)(X + i + 4);
    bf16x8 v;
    v[0]=(short)f2bf(a.x); v[1]=(short)f2bf(a.y); v[2]=(short)f2bf(a.z); v[3]=(short)f2bf(a.w);
    v[4]=(short)f2bf(v2.x); v[5]=(short)f2bf(v2.y); v[6]=(short)f2bf(v2.z); v[7]=(short)f2bf(v2.w);
    *(bf16x8*)(Xb + i) = v;
    return;
  }
  if (b < 1024 + 832){
    const int idx = b - 1024;
    const int k0 = (idx & 15) * 64, c0 = (idx >> 4) * 64;
    {
      const int r = tid >> 2, cs = (tid & 3) << 4;
      #pragma unroll
      for (int q = 0; q < 4; ++q){
        const int c = c0 + cs + q * 4;
        f32x4 v;
        if (c < 1024){
          v = *(const f32x4*)(Wq + (size_t)(k0+r)*1024 + c);
          const float s = 0.125f * LOG2E;   // fold 1/sqrt(d) and log2e into Q
          v.x *= s; v.y *= s; v.z *= s; v.w *= s;
        }
        else if (c < 2048) v = *(const f32x4*)(Wk + (size_t)(k0+r)*1024 + (c-1024));
        else if (c < 3072) v = *(const f32x4*)(Wv + (size_t)(k0+r)*1024 + (c-2048));
        else if (c < 3232) v = *(const f32x4*)(Wr + (size_t)(k0+r)*160  + (c-3072));
        else               v = (f32x4){0.f,0.f,0.f,0.f};
        tile[r][cs+q*4+0]=v.x; tile[r][cs+q*4+1]=v.y; tile[r][cs+q*4+2]=v.z; tile[r][cs+q*4+3]=v.w;
      }
    }
    __syncthreads();
    const int c = tid >> 2, ks = (tid & 3) << 4;
    bf16x8 o0, o1;
    #pragma unroll
    for (int x = 0; x < 8; ++x) o0[x] = (short)f2bf(tile[ks + x][c]);
    #pragma unroll
    for (int x = 0; x < 8; ++x) o1[x] = (short)f2bf(tile[ks + 8 + x][c]);
    *(bf16x8*)(WbT + (size_t)(c0 + c) * 1024 + k0 + ks)     = o0;
    *(bf16x8*)(WbT + (size_t)(c0 + c) * 1024 + k0 + ks + 8) = o1;
    return;
  }
  if (b < 1024 + 832 + 256){
    const int idx = b - 1856;
    const int k0 = (idx & 15) * 64, c0 = (idx >> 4) * 64;
    {
      const int r = tid >> 2, cs = (tid & 3) << 4;
      #pragma unroll
      for (int q = 0; q < 4; ++q){
        f32x4 v = *(const f32x4*)(Wp + (size_t)(k0+r)*1024 + c0 + cs + q*4);
        tile[r][cs+q*4+0]=v.x; tile[r][cs+q*4+1]=v.y; tile[r][cs+q*4+2]=v.z; tile[r][cs+q*4+3]=v.w;
      }
    }
    __syncthreads();
    const int c = tid >> 2, ks = (tid & 3) << 4;
    bf16x8 o0, o1;
    #pragma unroll
    for (int x = 0; x < 8; ++x) o0[x] = (short)f2bf(tile[ks + x][c]);
    #pragma unroll
    for (int x = 0; x < 8; ++x) o1[x] = (short)f2bf(tile[ks + 8 + x][c]);
    *(bf16x8*)(WpT + (size_t)(c0 + c) * 1024 + k0 + ks)     = o0;
    *(bf16x8*)(WpT + (size_t)(c0 + c) * 1024 + k0 + ks + 8) = o1;
    return;
  }
  const int c = (b - 2112) * 256 + tid;
  if (c < 3328){
    float v = 0.f;
    if (c < 1024) v = bq[c] * 0.125f * LOG2E;
    else if (c >= 3072 && c < 3232) v = br[c - 3072];
    bias[c] = v;
  }
}

// ---------------- fused post kernel (vt_transpose | build_bndt) --------------

__global__ __launch_bounds__(256) void post_mega(
    const unsigned short* __restrict__ Y, const float* __restrict__ bnd,
    unsigned short* __restrict__ Vt, unsigned short* __restrict__ BndT)
{
  __shared__ unsigned short tile[64][72];
  const int b = blockIdx.x;
  const int tid = threadIdx.x;

  if (b < 512){
    const int h = b >> 5, t0 = (b & 31) * 64;
    {
      const int r = tid >> 2, cs = (tid & 3) << 4;
      const unsigned short* src = Y + (size_t)(t0 + r) * LDY2 + 2048 + h * 64 + cs;
      *(bf16x8*)&tile[r][cs]     = *(const bf16x8*)src;
      *(bf16x8*)&tile[r][cs + 8] = *(const bf16x8*)(src + 8);
    }
    __syncthreads();
    const int d = tid >> 2, ts = (tid & 3) << 4;
    bf16x8 o0, o1;
    #pragma unroll
    for (int x = 0; x < 8; ++x) o0[x] = (short)tile[ts + x][d];
    #pragma unroll
    for (int x = 0; x < 8; ++x) o1[x] = (short)tile[ts + 8 + x][d];
    *(bf16x8*)(Vt + (size_t)(h*64 + d) * 2048 + t0 + ts)     = o0;
    *(bf16x8*)(Vt + (size_t)(h*64 + d) * 2048 + t0 + ts + 8) = o1;
    return;
  }
  // BndT[t'][32] scaled by log2e (E contributes to exp2-domain logits)
  const int t = (b - 512) * 256 + tid;
  if (t >= 2176) return;
  const int rel = t - 64;
  unsigned short* dst = BndT + (size_t)t * 32;
  bf16x8 v0 = {}, v1 = {}, z = {};
  if (rel >= 0 && rel < 2048){
    #pragma unroll
    for (int n = 0; n < 8; ++n) v0[n] = (short)f2bf(bnd[n * 2048 + rel] * LOG2E);
    v1[0] = (short)f2bf(bnd[8 * 2048 + rel] * LOG2E);
    v1[1] = (short)f2bf(bnd[9 * 2048 + rel] * LOG2E);
  }
  *(bf16x8*)dst        = v0;
  *(bf16x8*)(dst + 8)  = v1;
  *(bf16x8*)(dst + 16) = z;
  *(bf16x8*)(dst + 24) = z;
}

// ---------------- bf16 MFMA GEMM, 64x128 tile (unified) ---------------------

__global__ __launch_bounds__(256) void gemm64(
    const unsigned short* __restrict__ A,
    const unsigned short* __restrict__ BT,
    const float* __restrict__ bias,
    void* __restrict__ C, int ldc, int out_f32)
{
  __shared__ unsigned short As[64 * 64];
  __shared__ unsigned short Bs[128 * 64];
  const int tid = threadIdx.x;
  const int w = tid >> 6, lane = tid & 63;
  const int lid = lane & 15, lgrp = lane >> 4;
  const int wm = w >> 1, wn = w & 1;
  const int row0 = blockIdx.y << 6, col0 = blockIdx.x << 7;
  const int sr = lane >> 3;
  const int sc = (lane & 7) ^ sr;

  f32x4 acc[2][4] = {};

  for (int k0 = 0; k0 < 1024; k0 += 64){
    #pragma unroll
    for (int it = 0; it < 2; ++it){
      const int r0w = (w << 4) + (it << 3);
      const int r = r0w + sr;
      __builtin_amdgcn_global_load_lds(GLB(A + (size_t)(row0 + r) * 1024 + k0 + (sc << 3)),
                                       LDSP(&As[r0w << 6]), 16, 0, 0);
    }
    #pragma unroll
    for (int it = 0; it < 4; ++it){
      const int r0w = (w << 5) + (it << 3);
      const int r = r0w + sr;
      __builtin_amdgcn_global_load_lds(GLB(BT + (size_t)(col0 + r) * 1024 + k0 + (sc << 3)),
                                       LDSP(&Bs[r0w << 6]), 16, 0, 0);
    }
    __syncthreads();

    bf16x8 af[2][2], bfr[4][2];
    #pragma unroll
    for (int m = 0; m < 2; ++m){
      const int ra = wm * 32 + m * 16 + lid;
      #pragma unroll
      for (int kk = 0; kk < 2; ++kk){
        const int kc = kk * 4 + lgrp;
        af[m][kk] = *(const bf16x8*)&As[(ra << 6) + ((kc ^ (lid & 7)) << 3)];
      }
    }
    #pragma unroll
    for (int n = 0; n < 4; ++n){
      const int rb = wn * 64 + n * 16 + lid;
      #pragma unroll
      for (int kk = 0; kk < 2; ++kk){
        const int kc = kk * 4 + lgrp;
        bfr[n][kk] = *(const bf16x8*)&Bs[(rb << 6) + ((kc ^ (lid & 7)) << 3)];
      }
    }
    #pragma unroll
    for (int m = 0; m < 2; ++m)
      #pragma unroll
      for (int n = 0; n < 4; ++n){
        acc[m][n] = MFMA16(af[m][0], bfr[n][0], acc[m][n]);
        acc[m][n] = MFMA16(af[m][1], bfr[n][1], acc[m][n]);
      }
    __syncthreads();
  }

  #pragma unroll
  for (int m = 0; m < 2; ++m){
    #pragma unroll
    for (int n = 0; n < 4; ++n){
      const int col = col0 + wn * 64 + n * 16 + lid;
      const float bv = bias[col];
      #pragma unroll
      for (int i = 0; i < 4; ++i){
        const int row = row0 + wm * 32 + m * 16 + lgrp * 4 + i;
        const float v = acc[m][n][i] + bv;
        if (out_f32) ((float*)C)[(size_t)row * ldc + col] = v;
        else ((unsigned short*)C)[(size_t)row * ldc + col] = f2bf(v);
      }
    }
  }
}

// ---------------- fused flash attention (r15 schedule, El [c][20] scratch) ---

__device__ __forceinline__ void stage_tile(
    const unsigned short* __restrict__ Y,
    const unsigned short* __restrict__ Vt,
    unsigned short* __restrict__ Ksb,
    unsigned short* __restrict__ Vsb,
    int j0, int h, int sr, int scc)
{
  #pragma unroll
  for (int st = 0; st < 8; ++st){
    const int r0w = st * 8;
    const int r = r0w + sr;
    __builtin_amdgcn_global_load_lds(
        GLB(Y + (size_t)(j0 + r) * LDY2 + 1024 + h*64 + (scc << 3)),
        LDSP(&Ksb[r0w << 6]), 16, 0, 0);
    __builtin_amdgcn_global_load_lds(
        GLB(Vt + (size_t)(h*64 + r) * 2048 + j0 + (scc << 3)),
        LDSP(&Vsb[r0w << 6]), 16, 0, 0);
  }
}

__device__ __forceinline__ void attn_tile_body(
    const unsigned short* __restrict__ Ksb,
    const unsigned short* __restrict__ Vsb,
    unsigned short* __restrict__ un,
    const bf16x8 (&bw)[5],
    const bf16x8 (&qf)[2], const bf16x8& rf,
    int lid, int lgrp,
    bool diag, int ql,
    float& m_i, float& l_i, f32x4 (&o)[4])
{
  // S^T = K Q^T : s[n4][i] = S[q=lid][j = n4*16 + lgrp*4 + i]  (exp2 domain)
  f32x4 s[4] = {};
  __builtin_amdgcn_s_setprio(1);
  #pragma unroll
  for (int kk = 0; kk < 2; ++kk){
    const int kc = kk * 4 + lgrp;
    #pragma unroll
    for (int n4 = 0; n4 < 4; ++n4){
      const bf16x8 kf = *(const bf16x8*)&Ksb[((n4*16 + lid) << 6) + ((kc ^ (lid & 7)) << 3)];
      s[n4] = MFMA16(kf, qf[kk], s[n4]);
    }
  }
  __builtin_amdgcn_s_setprio(0);

  // E window via MFMA. ef[i] = E[q' = lgrp*4+i][c = f*16+lid].
  // Scratch el[c][20] (row 40B): the 4 q' values are contiguous -> one
  // b64-packed MAY_ALIAS write per f (20 scalar stores -> 5 b64).
  #pragma unroll
  for (int f = 0; f < 5; ++f){
    f32x4 ef = {};
    ef = MFMA16(rf, bw[f], ef);
    const unsigned lo = ((unsigned)f2bf_rn(ef[0])) | (((unsigned)f2bf_rn(ef[1])) << 16);
    const unsigned hi = ((unsigned)f2bf_rn(ef[2])) | (((unsigned)f2bf_rn(ef[3])) << 16);
    const unsigned long long pk = ((unsigned long long)hi << 32) | lo;
    *(u64a*)&un[(f*16 + lid) * 20 + lgrp*4] = pk;   // may_alias: keeps order vs u16 reads
  }

  // bias gather + causal mask: E[q=lid][c = lid - jl + 63] at un[c*20 + lid]
  #pragma unroll
  for (int n4 = 0; n4 < 4; ++n4){
    #pragma unroll
    for (int i = 0; i < 4; ++i){
      const int jl = n4*16 + lgrp*4 + i;
      float v = s[n4][i] + bf2f(un[(lid - jl + 63) * 20 + lid]);
      if (diag && jl > ql) v = -1e9f;
      s[n4][i] = v;
    }
  }

  // in-register online softmax (exp2 domain), defer-max THR = 8*log2e
  float rm = s[0][0];
  #pragma unroll
  for (int n4 = 0; n4 < 4; ++n4)
    #pragma unroll
    for (int i = 0; i < 4; ++i) rm = fmaxf(rm, s[n4][i]);
  rm = fmaxf(rm, __shfl_xor(rm, 16));
  rm = fmaxf(rm, __shfl_xor(rm, 32));

  if (__all(rm - m_i <= 11.54f)){
    float rs = 0.f;
    #pragma unroll
    for (int n4 = 0; n4 < 4; ++n4)
      #pragma unroll
      for (int i = 0; i < 4; ++i){
        const float pv = __builtin_amdgcn_exp2f(s[n4][i] - m_i);
        s[n4][i] = pv;
        rs += pv;
      }
    rs += __shfl_xor(rs, 16);
    rs += __shfl_xor(rs, 32);
    l_i += rs;
  } else {
    const float mn = fmaxf(m_i, rm);
    const float sc_ = __builtin_amdgcn_exp2f(m_i - mn);
    m_i = mn;
    float rs = 0.f;
    #pragma unroll
    for (int n4 = 0; n4 < 4; ++n4)
      #pragma unroll
      for (int i = 0; i < 4; ++i){
        const float pv = __builtin_amdgcn_exp2f(s[n4][i] - mn);
        s[n4][i] = pv;
        rs += pv;
      }
    rs += __shfl_xor(rs, 16);
    rs += __shfl_xor(rs, 32);
    l_i = l_i * sc_ + rs;
    #pragma unroll
    for (int n4 = 0; n4 < 4; ++n4)
      #pragma unroll
      for (int i = 0; i < 4; ++i) o[n4][i] *= sc_;
  }

  // P -> wave-local LDS (union region; el reads above complete first)
  #pragma unroll
  for (int n4 = 0; n4 < 4; ++n4){
    const unsigned a = ((unsigned)f2bf_rn(s[n4][0])) | (((unsigned)f2bf_rn(s[n4][1])) << 16);
    const unsigned b = ((unsigned)f2bf_rn(s[n4][2])) | (((unsigned)f2bf_rn(s[n4][3])) << 16);
    const int chunk = (n4*2 + (lgrp >> 1)) ^ (lid & 7);
    const int base = (lid << 6) + (chunk << 3) + ((lgrp & 1) << 2);
    *(unsigned*)&un[base]     = a;
    *(unsigned*)&un[base + 2] = b;
  }

  // O^T += V^T P^T
  __builtin_amdgcn_s_setprio(1);
  #pragma unroll
  for (int kk = 0; kk < 2; ++kk){
    const int kc = kk * 4 + lgrp;
    const bf16x8 pb = *(const bf16x8*)&un[(lid << 6) + ((kc ^ (lid & 7)) << 3)];
    #pragma unroll
    for (int n4 = 0; n4 < 4; ++n4){
      const bf16x8 vf = *(const bf16x8*)&Vsb[((n4*16 + lid) << 6) + ((kc ^ (lid & 7)) << 3)];
      o[n4] = MFMA16(vf, pb, o[n4]);
    }
  }
  __builtin_amdgcn_s_setprio(0);
}

__global__ __launch_bounds__(128) void attn_mfma(
    const unsigned short* __restrict__ Y,
    const unsigned short* __restrict__ Vt,
    const unsigned short* __restrict__ BndT,
    unsigned short* __restrict__ AO)
{
  __shared__ unsigned short KV[4][4096];  // K(grp0), K(grp1), V(grp0), V(grp1)
  __shared__ unsigned short UN[2][1600];  // per-wave union: El [80][20] / Pl [16][64]

  const int id = blockIdx.x;
  const int h = id & 15;
  const int u = (id >> 4) & 3;            // quarter within the 64-row block
  const int tid = threadIdx.x;
  const int grp = tid >> 6;               // kv-parity stream (wave id)
  const int lane = tid & 63;
  const int lid = lane & 15, lgrp = lane >> 4;
  const int sr = lane >> 3;
  const int scc = (lane & 7) ^ sr;

  unsigned short* Ksg = &KV[grp][0];
  unsigned short* Vsg = &KV[2 + grp][0];
  unsigned short* un  = &UN[grp][0];

  const int ql = u * 16 + lid;            // local-64 q (same both segments)

  #pragma unroll
  for (int seg = 0; seg < 2; ++seg){
    const int qb = seg ? (id >> 6) : (31 - (id >> 6));   // qbA=31-p, qbB=p
    const int q0w = qb * 64 + u * 16;
    const int qrow = q0w + lid;
    const int nt = qb + 1;
    const int L = (nt + 1) >> 1;

    // loop-invariant fragments for this segment
    bf16x8 qf[2];
    #pragma unroll
    for (int kk = 0; kk < 2; ++kk)
      qf[kk] = *(const bf16x8*)(Y + (size_t)qrow * LDY2 + h*64 + ((kk*4 + lgrp) << 3));
    bf16x8 rf = {};
    {
      const unsigned* rp = (const unsigned*)(Y + (size_t)qrow * LDY2 + 3072 + h*10);
      if (lgrp == 0){
        #pragma unroll
        for (int x = 0; x < 4; ++x) ((unsigned*)&rf)[x] = rp[x];
      } else if (lgrp == 1){
        ((unsigned*)&rf)[0] = rp[4];
      }
    }

    float m_i = -INFINITY, l_i = 0.f;
    f32x4 o[4] = {};

    // independent per-wave kv stream: tiles kb = grp, grp+2, ...
    for (int it = 0; it < L; ++it){
      const int kb = 2 * it + grp;
      if (kb < nt){
        const int j0 = kb << 6;
        const int d0 = q0w - j0;

        stage_tile(Y, Vt, Ksg, Vsg, j0, h, sr, scc);

        bf16x8 bw[5];
        #pragma unroll
        for (int f = 0; f < 5; ++f){
          const int rowt = d0 + 1 + f * 16 + lid;     // rel + 64
          bw[f] = *(const bf16x8*)(BndT + ((size_t)rowt << 5) + (lgrp << 3));
        }

        asm volatile("s_waitcnt vmcnt(0)" ::: "memory");
        __builtin_amdgcn_sched_barrier(0);

        attn_tile_body(Ksg, Vsg, un, bw, qf, rf, lid, lgrp,
                       kb == qb, ql, m_i, l_i, o);
      }
    }

    // ---- exact 2-way merge of the parity streams (in LDS) ----
    float* oScr  = (float*)&KV[1][0];     // 16 q x 64 d f32 (grp1's K buf)
    float* mlScr = (float*)&KV[3][0];     // 16 q x 2 f32 (grp1's V buf)
    if (grp == 1){
      #pragma unroll
      for (int n4 = 0; n4 < 4; ++n4)
        *(f32x4*)&oScr[lid * 64 + n4*16 + lgrp*4] = o[n4];
      if (lgrp == 0){
        mlScr[lid * 2 + 0] = m_i;
        mlScr[lid * 2 + 1] = l_i;
      }
    }
    __syncthreads();
    if (grp == 0){
      const float m1 = mlScr[lid * 2 + 0];
      const float l1 = mlScr[lid * 2 + 1];
      const float M  = fmaxf(m_i, m1);
      const float a  = __builtin_amdgcn_exp2f(m_i - M);
      const float b  = __builtin_amdgcn_exp2f(m1 - M);
      const float inv = 1.f / (l_i * a + l1 * b);
      unsigned short* dst = AO + (size_t)qrow * 1024 + h * 64;
      #pragma unroll
      for (int n4 = 0; n4 < 4; ++n4){
        const f32x4 o1 = *(const f32x4*)&oScr[lid * 64 + n4*16 + lgrp*4];
        const float v0 = (o[n4][0]*a + o1[0]*b) * inv;
        const float v1 = (o[n4][1]*a + o1[1]*b) * inv;
        const float v2 = (o[n4][2]*a + o1[2]*b) * inv;
        const float v3 = (o[n4][3]*a + o1[3]*b) * inv;
        unsigned r0 = ((unsigned)f2bf_rn(v0)) | (((unsigned)f2bf_rn(v1)) << 16);
        unsigned r1 = ((unsigned)f2bf_rn(v2)) | (((unsigned)f2bf_rn(v3)) << 16);
        unsigned long long pk = ((unsigned long long)r1 << 32) | r0;
        *(u64a*)(dst + n4*16 + lgrp*4) = pk;
      }
    }
    __syncthreads();   // scratch (KV[1]/KV[3]) free before next segment staging
  }
}

// ---------------- launch ----------------

extern "C" void kernel_launch(void* const* d_in, const int* in_sizes, int n_in,
                              void* d_out, int out_size, void* d_ws, size_t ws_size,
                              hipStream_t stream) {
  const float* X   = (const float*)d_in[0];
  const float* Wq  = (const float*)d_in[1];
  const float* bq  = (const float*)d_in[2];
  const float* Wk  = (const float*)d_in[3];
  const float* Wv  = (const float*)d_in[4];
  const float* Wp  = (const float*)d_in[5];
  const float* bp  = (const float*)d_in[6];
  const float* Wr  = (const float*)d_in[7];
  const float* br  = (const float*)d_in[8];
  const float* bnd = (const float*)d_in[9];
  float* out = (float*)d_out;

  unsigned short* Xb  = (unsigned short*)d_ws;            // 2048*1024 (reused as AO)
  unsigned short* WbT = Xb  + (size_t)2048 * 1024;        // 3328*1024
  unsigned short* Yb  = WbT + (size_t)3328 * 1024;        // 2048*3328
  unsigned short* Vt  = Yb  + (size_t)2048 * 3328;        // 1024*2048
  unsigned short* WpT = Vt  + (size_t)1024 * 2048;        // 1024*1024
  float* bias = (float*)(WpT + (size_t)1024 * 1024);      // 3328
  unsigned short* AO   = Xb;                    // Xb dead after gemm1
  unsigned short* BndT = WbT + (size_t)3232 * 1024;  // WbT pad rows (dead after gemm1)

  prep_mega <<<2125,         256, 0, stream>>>(X, Wq, Wk, Wv, Wr, Wp, bq, br,
                                               Xb, WbT, WpT, bias);
  gemm64    <<<dim3(26, 32), 256, 0, stream>>>(Xb, WbT, bias, Yb, 3328, 0);
  post_mega <<<521,          256, 0, stream>>>(Yb, bnd, Vt, BndT);
  attn_mfma <<<1024,         128, 0, stream>>>(Yb, Vt, BndT, AO);
  gemm64    <<<dim3(8, 32),  256, 0, stream>>>(AO, WpT, bp, out, 1024, 1);
}

// Round 19
// 98.142 us; speedup vs baseline: 1.3476x; 1.0210x over previous
//
#include <hip/hip_runtime.h>
#include <hip/hip_bf16.h>
#include <math.h>

// Problem: B=1, T=2048, E=1024, H=16, DH=64, NB=10, ML=2048
// Pipeline (all bf16 MFMA), 4 kernels:
//   prep_mega: Xb = bf16(X); WbT = [Wq*0.125*log2e|Wk|Wv|Wr]^T (rows<3232);
//              WpT; bias; BndT*log2e (in WbT pad rows - only BndT writes there)
//   gemm64 (64x128, 832 blocks): Y = Xb @ Wb + bias; V-col blocks also emit
//              Vt[h][d][t] transposed in the epilogue (replaces post_mega)
//   attn: r18 structure: independent kv-parity wave-streams, uniform 17 iters,
//         El [c][20] packed scratch, exp2 softmax, DIAG-specialized body
//   gemm64 (64x128, 256 blocks): out = AO @ Wp + bp (f32)

typedef __attribute__((ext_vector_type(8))) short bf16x8;
typedef __attribute__((ext_vector_type(4))) float f32x4;
typedef unsigned long long __attribute__((may_alias)) u64a;

#define MFMA16(a,b,c) __builtin_amdgcn_mfma_f32_16x16x32_bf16((a),(b),(c),0,0,0)
#define GLB(p)  ((const __attribute__((address_space(1))) void*)(p))
#define LDSP(p) ((__attribute__((address_space(3))) void*)(p))
#define LDY2 3328
#define LOG2E 1.44269504088896f

__device__ __forceinline__ unsigned short f2bf(float x){
  unsigned u = __float_as_uint(x);
  u = (u + 0x7FFFu + ((u >> 16) & 1u)) >> 16;
  return (unsigned short)u;
}
__device__ __forceinline__ unsigned short f2bf_rn(float x){
  __hip_bfloat16 b = __float2bfloat16(x);
  return *reinterpret_cast<unsigned short*>(&b);
}
__device__ __forceinline__ float bf2f(unsigned short b){
  return __uint_as_float(((unsigned)b) << 16);
}

// -------- prep kernel (convert_x | pack_wbt | transpose_wp | bias | bndt) ----

__global__ __launch_bounds__(256) void prep_mega(
    const float* __restrict__ X,
    const float* __restrict__ Wq, const float* __restrict__ Wk,
    const float* __restrict__ Wv, const float* __restrict__ Wr,
    const float* __restrict__ Wp,
    const float* __restrict__ bq, const float* __restrict__ br,
    const float* __restrict__ bnd,
    unsigned short* __restrict__ Xb, unsigned short* __restrict__ WbT,
    unsigned short* __restrict__ WpT, float* __restrict__ bias,
    unsigned short* __restrict__ BndT)
{
  __shared__ float tile[64][65];
  const int b = blockIdx.x;
  const int tid = threadIdx.x;

  if (b < 1024){
    const int i = (b * 256 + tid) * 8;
    f32x4 a = *(const f32x4*)(X + i);
    f32x4 v2 = *(const f32x4*)(X + i + 4);
    bf16x8 v;
    v[0]=(short)f2bf(a.x); v[1]=(short)f2bf(a.y); v[2]=(short)f2bf(a.z); v[3]=(short)f2bf(a.w);
    v[4]=(short)f2bf(v2.x); v[5]=(short)f2bf(v2.y); v[6]=(short)f2bf(v2.z); v[7]=(short)f2bf(v2.w);
    *(bf16x8*)(Xb + i) = v;
    return;
  }
  if (b < 1024 + 832){
    const int idx = b - 1024;
    const int k0 = (idx & 15) * 64, c0 = (idx >> 4) * 64;
    {
      const int r = tid >> 2, cs = (tid & 3) << 4;
      #pragma unroll
      for (int q = 0; q < 4; ++q){
        const int c = c0 + cs + q * 4;
        f32x4 v;
        if (c < 1024){
          v = *(const f32x4*)(Wq + (size_t)(k0+r)*1024 + c);
          const float s = 0.125f * LOG2E;   // fold 1/sqrt(d) and log2e into Q
          v.x *= s; v.y *= s; v.z *= s; v.w *= s;
        }
        else if (c < 2048) v = *(const f32x4*)(Wk + (size_t)(k0+r)*1024 + (c-1024));
        else if (c < 3072) v = *(const f32x4*)(Wv + (size_t)(k0+r)*1024 + (c-2048));
        else if (c < 3232) v = *(const f32x4*)(Wr + (size_t)(k0+r)*160  + (c-3072));
        else               v = (f32x4){0.f,0.f,0.f,0.f};
        tile[r][cs+q*4+0]=v.x; tile[r][cs+q*4+1]=v.y; tile[r][cs+q*4+2]=v.z; tile[r][cs+q*4+3]=v.w;
      }
    }
    __syncthreads();
    const int c = tid >> 2, ks = (tid & 3) << 4;
    if (c0 + c < 3232){     // rows >= 3232 belong to BndT (written elsewhere)
      bf16x8 o0, o1;
      #pragma unroll
      for (int x = 0; x < 8; ++x) o0[x] = (short)f2bf(tile[ks + x][c]);
      #pragma unroll
      for (int x = 0; x < 8; ++x) o1[x] = (short)f2bf(tile[ks + 8 + x][c]);
      *(bf16x8*)(WbT + (size_t)(c0 + c) * 1024 + k0 + ks)     = o0;
      *(bf16x8*)(WbT + (size_t)(c0 + c) * 1024 + k0 + ks + 8) = o1;
    }
    return;
  }
  if (b < 1024 + 832 + 256){
    const int idx = b - 1856;
    const int k0 = (idx & 15) * 64, c0 = (idx >> 4) * 64;
    {
      const int r = tid >> 2, cs = (tid & 3) << 4;
      #pragma unroll
      for (int q = 0; q < 4; ++q){
        f32x4 v = *(const f32x4*)(Wp + (size_t)(k0+r)*1024 + c0 + cs + q*4);
        tile[r][cs+q*4+0]=v.x; tile[r][cs+q*4+1]=v.y; tile[r][cs+q*4+2]=v.z; tile[r][cs+q*4+3]=v.w;
      }
    }
    __syncthreads();
    const int c = tid >> 2, ks = (tid & 3) << 4;
    bf16x8 o0, o1;
    #pragma unroll
    for (int x = 0; x < 8; ++x) o0[x] = (short)f2bf(tile[ks + x][c]);
    #pragma unroll
    for (int x = 0; x < 8; ++x) o1[x] = (short)f2bf(tile[ks + 8 + x][c]);
    *(bf16x8*)(WpT + (size_t)(c0 + c) * 1024 + k0 + ks)     = o0;
    *(bf16x8*)(WpT + (size_t)(c0 + c) * 1024 + k0 + ks + 8) = o1;
    return;
  }
  if (b < 2125){
    const int c = (b - 2112) * 256 + tid;
    if (c < 3328){
      float v = 0.f;
      if (c < 1024) v = bq[c] * 0.125f * LOG2E;
      else if (c >= 3072 && c < 3232) v = br[c - 3072];
      bias[c] = v;
    }
    return;
  }
  // BndT[t'][32] scaled by log2e; t' = rel + 64 in [0,2176)
  const int t = (b - 2125) * 256 + tid;
  if (t >= 2176) return;
  const int rel = t - 64;
  unsigned short* dst = BndT + (size_t)t * 32;
  bf16x8 v0 = {}, v1 = {}, z = {};
  if (rel >= 0 && rel < 2048){
    #pragma unroll
    for (int n = 0; n < 8; ++n) v0[n] = (short)f2bf(bnd[n * 2048 + rel] * LOG2E);
    v1[0] = (short)f2bf(bnd[8 * 2048 + rel] * LOG2E);
    v1[1] = (short)f2bf(bnd[9 * 2048 + rel] * LOG2E);
  }
  *(bf16x8*)dst        = v0;
  *(bf16x8*)(dst + 8)  = v1;
  *(bf16x8*)(dst + 16) = z;
  *(bf16x8*)(dst + 24) = z;
}

// ---------------- bf16 MFMA GEMM, 64x128 tile (unified) ---------------------
// If VtOut != nullptr, blocks covering cols [2048,3072) also store the tile
// transposed: Vt[(col-2048)*2048 + row] (replaces the vt_transpose pass).

__global__ __launch_bounds__(256) void gemm64(
    const unsigned short* __restrict__ A,
    const unsigned short* __restrict__ BT,
    const float* __restrict__ bias,
    void* __restrict__ C, int ldc, int out_f32,
    unsigned short* __restrict__ VtOut)
{
  __shared__ unsigned short As[64 * 64];
  __shared__ unsigned short Bs[128 * 64];
  const int tid = threadIdx.x;
  const int w = tid >> 6, lane = tid & 63;
  const int lid = lane & 15, lgrp = lane >> 4;
  const int wm = w >> 1, wn = w & 1;
  const int row0 = blockIdx.y << 6, col0 = blockIdx.x << 7;
  const int sr = lane >> 3;
  const int sc = (lane & 7) ^ sr;
  const bool do_vt = (VtOut != nullptr) && (col0 >= 2048) && (col0 < 3072);

  f32x4 acc[2][4] = {};

  for (int k0 = 0; k0 < 1024; k0 += 64){
    #pragma unroll
    for (int it = 0; it < 2; ++it){
      const int r0w = (w << 4) + (it << 3);
      const int r = r0w + sr;
      __builtin_amdgcn_global_load_lds(GLB(A + (size_t)(row0 + r) * 1024 + k0 + (sc << 3)),
                                       LDSP(&As[r0w << 6]), 16, 0, 0);
    }
    #pragma unroll
    for (int it = 0; it < 4; ++it){
      const int r0w = (w << 5) + (it << 3);
      const int r = r0w + sr;
      __builtin_amdgcn_global_load_lds(GLB(BT + (size_t)(col0 + r) * 1024 + k0 + (sc << 3)),
                                       LDSP(&Bs[r0w << 6]), 16, 0, 0);
    }
    __syncthreads();

    bf16x8 af[2][2], bfr[4][2];
    #pragma unroll
    for (int m = 0; m < 2; ++m){
      const int ra = wm * 32 + m * 16 + lid;
      #pragma unroll
      for (int kk = 0; kk < 2; ++kk){
        const int kc = kk * 4 + lgrp;
        af[m][kk] = *(const bf16x8*)&As[(ra << 6) + ((kc ^ (lid & 7)) << 3)];
      }
    }
    #pragma unroll
    for (int n = 0; n < 4; ++n){
      const int rb = wn * 64 + n * 16 + lid;
      #pragma unroll
      for (int kk = 0; kk < 2; ++kk){
        const int kc = kk * 4 + lgrp;
        bfr[n][kk] = *(const bf16x8*)&Bs[(rb << 6) + ((kc ^ (lid & 7)) << 3)];
      }
    }
    #pragma unroll
    for (int m = 0; m < 2; ++m)
      #pragma unroll
      for (int n = 0; n < 4; ++n){
        acc[m][n] = MFMA16(af[m][0], bfr[n][0], acc[m][n]);
        acc[m][n] = MFMA16(af[m][1], bfr[n][1], acc[m][n]);
      }
    __syncthreads();
  }

  #pragma unroll
  for (int m = 0; m < 2; ++m){
    #pragma unroll
    for (int n = 0; n < 4; ++n){
      const int col = col0 + wn * 64 + n * 16 + lid;
      const float bv = bias[col];
      const int rowb = row0 + wm * 32 + m * 16 + lgrp * 4;
      unsigned short bf[4];
      #pragma unroll
      for (int i = 0; i < 4; ++i){
        const float v = acc[m][n][i] + bv;
        if (out_f32) ((float*)C)[(size_t)(rowb + i) * ldc + col] = v;
        else {
          bf[i] = f2bf(v);
          ((unsigned short*)C)[(size_t)(rowb + i) * ldc + col] = bf[i];
        }
      }
      if (do_vt){
        // Vt[(col-2048)*2048 + row], 4 consecutive rows -> one 8B store
        const unsigned long long pk =
            ((unsigned long long)bf[0])        | (((unsigned long long)bf[1]) << 16) |
            (((unsigned long long)bf[2]) << 32) | (((unsigned long long)bf[3]) << 48);
        *(u64a*)(VtOut + (size_t)(col - 2048) * 2048 + rowb) = pk;
      }
    }
  }
}

// ---------------- fused flash attention (r18 + DIAG specialization) ----------

__device__ __forceinline__ void stage_tile(
    const unsigned short* __restrict__ Y,
    const unsigned short* __restrict__ Vt,
    unsigned short* __restrict__ Ksb,
    unsigned short* __restrict__ Vsb,
    int j0, int h, int sr, int scc)
{
  #pragma unroll
  for (int st = 0; st < 8; ++st){
    const int r0w = st * 8;
    const int r = r0w + sr;
    __builtin_amdgcn_global_load_lds(
        GLB(Y + (size_t)(j0 + r) * LDY2 + 1024 + h*64 + (scc << 3)),
        LDSP(&Ksb[r0w << 6]), 16, 0, 0);
    __builtin_amdgcn_global_load_lds(
        GLB(Vt + (size_t)(h*64 + r) * 2048 + j0 + (scc << 3)),
        LDSP(&Vsb[r0w << 6]), 16, 0, 0);
  }
}

template<bool DIAG>
__device__ __forceinline__ void attn_tile_body(
    const unsigned short* __restrict__ Ksb,
    const unsigned short* __restrict__ Vsb,
    unsigned short* __restrict__ un,
    const bf16x8 (&bw)[5],
    const bf16x8 (&qf)[2], const bf16x8& rf,
    int lid, int lgrp, int ql,
    float& m_i, float& l_i, f32x4 (&o)[4])
{
  // S^T = K Q^T : s[n4][i] = S[q=lid][j = n4*16 + lgrp*4 + i]  (exp2 domain)
  f32x4 s[4] = {};
  __builtin_amdgcn_s_setprio(1);
  #pragma unroll
  for (int kk = 0; kk < 2; ++kk){
    const int kc = kk * 4 + lgrp;
    #pragma unroll
    for (int n4 = 0; n4 < 4; ++n4){
      const bf16x8 kf = *(const bf16x8*)&Ksb[((n4*16 + lid) << 6) + ((kc ^ (lid & 7)) << 3)];
      s[n4] = MFMA16(kf, qf[kk], s[n4]);
    }
  }
  __builtin_amdgcn_s_setprio(0);

  // E window via MFMA; scratch el[c][20], one b64 may_alias write per f
  #pragma unroll
  for (int f = 0; f < 5; ++f){
    f32x4 ef = {};
    ef = MFMA16(rf, bw[f], ef);
    const unsigned lo = ((unsigned)f2bf_rn(ef[0])) | (((unsigned)f2bf_rn(ef[1])) << 16);
    const unsigned hi = ((unsigned)f2bf_rn(ef[2])) | (((unsigned)f2bf_rn(ef[3])) << 16);
    const unsigned long long pk = ((unsigned long long)hi << 32) | lo;
    *(u64a*)&un[(f*16 + lid) * 20 + lgrp*4] = pk;
  }

  // bias gather (+ causal mask only on the diagonal tile)
  #pragma unroll
  for (int n4 = 0; n4 < 4; ++n4){
    #pragma unroll
    for (int i = 0; i < 4; ++i){
      const int jl = n4*16 + lgrp*4 + i;
      float v = s[n4][i] + bf2f(un[(lid - jl + 63) * 20 + lid]);
      if (DIAG && jl > ql) v = -1e9f;
      s[n4][i] = v;
    }
  }

  // in-register online softmax (exp2 domain), defer-max THR = 8*log2e
  float rm = s[0][0];
  #pragma unroll
  for (int n4 = 0; n4 < 4; ++n4)
    #pragma unroll
    for (int i = 0; i < 4; ++i) rm = fmaxf(rm, s[n4][i]);
  rm = fmaxf(rm, __shfl_xor(rm, 16));
  rm = fmaxf(rm, __shfl_xor(rm, 32));

  if (__all(rm - m_i <= 11.54f)){
    float rs = 0.f;
    #pragma unroll
    for (int n4 = 0; n4 < 4; ++n4)
      #pragma unroll
      for (int i = 0; i < 4; ++i){
        const float pv = __builtin_amdgcn_exp2f(s[n4][i] - m_i);
        s[n4][i] = pv;
        rs += pv;
      }
    rs += __shfl_xor(rs, 16);
    rs += __shfl_xor(rs, 32);
    l_i += rs;
  } else {
    const float mn = fmaxf(m_i, rm);
    const float sc_ = __builtin_amdgcn_exp2f(m_i - mn);
    m_i = mn;
    float rs = 0.f;
    #pragma unroll
    for (int n4 = 0; n4 < 4; ++n4)
      #pragma unroll
      for (int i = 0; i < 4; ++i){
        const float pv = __builtin_amdgcn_exp2f(s[n4][i] - mn);
        s[n4][i] = pv;
        rs += pv;
      }
    rs += __shfl_xor(rs, 16);
    rs += __shfl_xor(rs, 32);
    l_i = l_i * sc_ + rs;
    #pragma unroll
    for (int n4 = 0; n4 < 4; ++n4)
      #pragma unroll
      for (int i = 0; i < 4; ++i) o[n4][i] *= sc_;
  }

  // P -> wave-local LDS (union region; el reads above complete first)
  #pragma unroll
  for (int n4 = 0; n4 < 4; ++n4){
    const unsigned a = ((unsigned)f2bf_rn(s[n4][0])) | (((unsigned)f2bf_rn(s[n4][1])) << 16);
    const unsigned b = ((unsigned)f2bf_rn(s[n4][2])) | (((unsigned)f2bf_rn(s[n4][3])) << 16);
    const int chunk = (n4*2 + (lgrp >> 1)) ^ (lid & 7);
    const int base = (lid << 6) + (chunk << 3) + ((lgrp & 1) << 2);
    *(unsigned*)&un[base]     = a;
    *(unsigned*)&un[base + 2] = b;
  }

  // O^T += V^T P^T
  __builtin_amdgcn_s_setprio(1);
  #pragma unroll
  for (int kk = 0; kk < 2; ++kk){
    const int kc = kk * 4 + lgrp;
    const bf16x8 pb = *(const bf16x8*)&un[(lid << 6) + ((kc ^ (lid & 7)) << 3)];
    #pragma unroll
    for (int n4 = 0; n4 < 4; ++n4){
      const bf16x8 vf = *(const bf16x8*)&Vsb[((n4*16 + lid) << 6) + ((kc ^ (lid & 7)) << 3)];
      o[n4] = MFMA16(vf, pb, o[n4]);
    }
  }
  __builtin_amdgcn_s_setprio(0);
}

__global__ __launch_bounds__(128) void attn_mfma(
    const unsigned short* __restrict__ Y,
    const unsigned short* __restrict__ Vt,
    const unsigned short* __restrict__ BndT,
    unsigned short* __restrict__ AO)
{
  __shared__ unsigned short KV[4][4096];  // K(grp0), K(grp1), V(grp0), V(grp1)
  __shared__ unsigned short UN[2][1600];  // per-wave union: El [80][20] / Pl [16][64]

  const int id = blockIdx.x;
  const int h = id & 15;
  const int u = (id >> 4) & 3;            // quarter within the 64-row block
  const int tid = threadIdx.x;
  const int grp = tid >> 6;               // kv-parity stream (wave id)
  const int lane = tid & 63;
  const int lid = lane & 15, lgrp = lane >> 4;
  const int sr = lane >> 3;
  const int scc = (lane & 7) ^ sr;

  unsigned short* Ksg = &KV[grp][0];
  unsigned short* Vsg = &KV[2 + grp][0];
  unsigned short* un  = &UN[grp][0];

  const int ql = u * 16 + lid;            // local-64 q (same both segments)

  #pragma unroll
  for (int seg = 0; seg < 2; ++seg){
    const int qb = seg ? (id >> 6) : (31 - (id >> 6));   // qbA=31-p, qbB=p
    const int q0w = qb * 64 + u * 16;
    const int qrow = q0w + lid;
    const int nt = qb + 1;
    const int L = (nt + 1) >> 1;

    // loop-invariant fragments for this segment
    bf16x8 qf[2];
    #pragma unroll
    for (int kk = 0; kk < 2; ++kk)
      qf[kk] = *(const bf16x8*)(Y + (size_t)qrow * LDY2 + h*64 + ((kk*4 + lgrp) << 3));
    bf16x8 rf = {};
    {
      const unsigned* rp = (const unsigned*)(Y + (size_t)qrow * LDY2 + 3072 + h*10);
      if (lgrp == 0){
        #pragma unroll
        for (int x = 0; x < 4; ++x) ((unsigned*)&rf)[x] = rp[x];
      } else if (lgrp == 1){
        ((unsigned*)&rf)[0] = rp[4];
      }
    }

    float m_i = -INFINITY, l_i = 0.f;
    f32x4 o[4] = {};

    // independent per-wave kv stream: tiles kb = grp, grp+2, ...
    for (int it = 0; it < L; ++it){
      const int kb = 2 * it + grp;
      if (kb < nt){
        const int j0 = kb << 6;
        const int d0 = q0w - j0;

        stage_tile(Y, Vt, Ksg, Vsg, j0, h, sr, scc);

        bf16x8 bw[5];
        #pragma unroll
        for (int f = 0; f < 5; ++f){
          const int rowt = d0 + 1 + f * 16 + lid;     // rel + 64
          bw[f] = *(const bf16x8*)(BndT + ((size_t)rowt << 5) + (lgrp << 3));
        }

        asm volatile("s_waitcnt vmcnt(0)" ::: "memory");
        __builtin_amdgcn_sched_barrier(0);

        if (kb == qb)
          attn_tile_body<true >(Ksg, Vsg, un, bw, qf, rf, lid, lgrp, ql, m_i, l_i, o);
        else
          attn_tile_body<false>(Ksg, Vsg, un, bw, qf, rf, lid, lgrp, ql, m_i, l_i, o);
      }
    }

    // ---- exact 2-way merge of the parity streams (in LDS) ----
    float* oScr  = (float*)&KV[1][0];     // 16 q x 64 d f32 (grp1's K buf)
    float* mlScr = (float*)&KV[3][0];     // 16 q x 2 f32 (grp1's V buf)
    if (grp == 1){
      #pragma unroll
      for (int n4 = 0; n4 < 4; ++n4)
        *(f32x4*)&oScr[lid * 64 + n4*16 + lgrp*4] = o[n4];
      if (lgrp == 0){
        mlScr[lid * 2 + 0] = m_i;
        mlScr[lid * 2 + 1] = l_i;
      }
    }
    __syncthreads();
    if (grp == 0){
      const float m1 = mlScr[lid * 2 + 0];
      const float l1 = mlScr[lid * 2 + 1];
      const float M  = fmaxf(m_i, m1);
      const float a  = __builtin_amdgcn_exp2f(m_i - M);
      const float b  = __builtin_amdgcn_exp2f(m1 - M);
      const float inv = 1.f / (l_i * a + l1 * b);
      unsigned short* dst = AO + (size_t)qrow * 1024 + h * 64;
      #pragma unroll
      for (int n4 = 0; n4 < 4; ++n4){
        const f32x4 o1 = *(const f32x4*)&oScr[lid * 64 + n4*16 + lgrp*4];
        const float v0 = (o[n4][0]*a + o1[0]*b) * inv;
        const float v1 = (o[n4][1]*a + o1[1]*b) * inv;
        const float v2 = (o[n4][2]*a + o1[2]*b) * inv;
        const float v3 = (o[n4][3]*a + o1[3]*b) * inv;
        unsigned r0 = ((unsigned)f2bf_rn(v0)) | (((unsigned)f2bf_rn(v1)) << 16);
        unsigned r1 = ((unsigned)f2bf_rn(v2)) | (((unsigned)f2bf_rn(v3)) << 16);
        unsigned long long pk = ((unsigned long long)r1 << 32) | r0;
        *(u64a*)(dst + n4*16 + lgrp*4) = pk;
      }
    }
    __syncthreads();   // scratch (KV[1]/KV[3]) free before next segment staging
  }
}

// ---------------- launch ----------------

extern "C" void kernel_launch(void* const* d_in, const int* in_sizes, int n_in,
                              void* d_out, int out_size, void* d_ws, size_t ws_size,
                              hipStream_t stream) {
  const float* X   = (const float*)d_in[0];
  const float* Wq  = (const float*)d_in[1];
  const float* bq  = (const float*)d_in[2];
  const float* Wk  = (const float*)d_in[3];
  const float* Wv  = (const float*)d_in[4];
  const float* Wp  = (const float*)d_in[5];
  const float* bp  = (const float*)d_in[6];
  const float* Wr  = (const float*)d_in[7];
  const float* br  = (const float*)d_in[8];
  const float* bnd = (const float*)d_in[9];
  float* out = (float*)d_out;

  unsigned short* Xb  = (unsigned short*)d_ws;            // 2048*1024 (reused as AO)
  unsigned short* WbT = Xb  + (size_t)2048 * 1024;        // 3328*1024
  unsigned short* Yb  = WbT + (size_t)3328 * 1024;        // 2048*3328
  unsigned short* Vt  = Yb  + (size_t)2048 * 3328;        // 1024*2048
  unsigned short* WpT = Vt  + (size_t)1024 * 2048;        // 1024*1024
  float* bias = (float*)(WpT + (size_t)1024 * 1024);      // 3328
  unsigned short* AO   = Xb;                    // Xb dead after gemm1
  unsigned short* BndT = WbT + (size_t)3232 * 1024;  // WbT pad rows (BndT-only)

  prep_mega <<<2134,         256, 0, stream>>>(X, Wq, Wk, Wv, Wr, Wp, bq, br, bnd,
                                               Xb, WbT, WpT, bias, BndT);
  gemm64    <<<dim3(26, 32), 256, 0, stream>>>(Xb, WbT, bias, Yb, 3328, 0, Vt);
  attn_mfma <<<1024,         128, 0, stream>>>(Yb, Vt, BndT, AO);
  gemm64    <<<dim3(8, 32),  256, 0, stream>>>(AO, WpT, bp, out, 1024, 1, nullptr);
}